// Round 8
// baseline (982.109 us; speedup 1.0000x reference)
//
#include <hip/hip_runtime.h>
#include <hip/hip_bf16.h>
#include <math.h>

// Problem constants
#define BB 4
#define SS 4096
#define DD 1024
#define NN 128           // D / 8
#define KLV 8            // quantization levels
#define MM (BB*SS)       // 16384 rows
#define KDIM (2*DD)      // 2048 GEMM K
// GEMM tiling
#define Bb_M 128
#define Bb_N 128
#define Bb_K 16

// Static device scratch.
__device__ float g_U[KLV * NN * 128];            // 512 KB  Cayley table
__device__ unsigned char g_levels[MM * NN];      // 2 MB    per-(token,block) level

// f32 -> bf16 bits, round-to-nearest-even
__device__ __forceinline__ unsigned int bf16_bits(float f) {
    union { float f; unsigned int u; } v;
    v.f = f;
    unsigned int lsb = (v.u >> 16) & 1u;
    return (v.u + 0x7FFFu + lsb) >> 16;
}

// ---------------------------------------------------------------------------
// Kernel A: Cayley table (Gauss-Jordan, 16x16 augmented, no pivoting).
//   g_U[(L*128+n)*128 + 0..63]  = U_r row-major [o][i]
//   g_U[(L*128+n)*128 + 64..127]= U_i row-major [o][i]
// ---------------------------------------------------------------------------
__global__ __launch_bounds__(256)
void cayley_kernel(const float* __restrict__ A_real,
                   const float* __restrict__ A_imag)
{
    int idx = blockIdx.x;            // 0..1023  = L*128 + n
    int L = idx >> 7;
    int n = idx & 127;
    float g = (float)L * (1.0f / 7.0f);

    __shared__ float M[16][34];      // [LHS | RHS] augmented, padded

    int tid = threadIdx.x;           // 256 = 16 x 16
    int i = tid >> 4;                // row 0..15
    int j = tid & 15;                // col 0..15

    const float* Ar = A_real + n * 64;
    const float* Ai = A_imag + n * 64;
    int bi = i >> 3;
    int ii = i & 7, jj = j & 7;

    float ar = (Ar[ii * 8 + jj] - Ar[jj * 8 + ii]) * 0.5f * g;  // antisym
    float ai = (Ai[ii * 8 + jj] + Ai[jj * 8 + ii]) * 0.5f * g;  // sym
    float eye = (ii == jj) ? 1.0f : 0.0f;

    int bj = j >> 3;
    float lhs, rhs;
    if (bi == bj) { lhs = eye + ar; rhs = eye - ar; }       // diagonal blocks
    else if (bi == 0) { lhs = -ai; rhs = ai; }              // top-right
    else { lhs = ai; rhs = -ai; }                           // bottom-left

    M[i][j] = lhs;
    M[i][16 + j] = rhs;
    __syncthreads();

    for (int k = 0; k < 16; ++k) {
        float f = M[i][k] / M[k][k];
        __syncthreads();
        if (i != k) {
            M[i][j]      -= f * M[k][j];
            M[i][16 + j] -= f * M[k][16 + j];
        }
        __syncthreads();
    }

    float x = M[i][16 + j] / M[i][i];
    if (j < 8) {
        g_U[(size_t)idx * 128 + bi * 64 + ii * 8 + j] = x;
    }
}

// ---------------------------------------------------------------------------
// Kernel B: gate GEMM (f32 vector ALU) + sigmoid + 8-col mean + quantize.
// ---------------------------------------------------------------------------
__global__ __launch_bounds__(256)
void gate_kernel(const float* __restrict__ xr,
                 const float* __restrict__ xi,
                 const float* __restrict__ W,
                 const float* __restrict__ bias)
{
    __shared__ float As[Bb_K][132];   // transposed A tile: As[kk][m]
    __shared__ float Bs[Bb_K][132];   // Bs[kk][n]

    int tid = threadIdx.x;
    int bm = blockIdx.y * Bb_M;
    int bn = blockIdx.x * Bb_N;

    float c[8][8];
    #pragma unroll
    for (int a = 0; a < 8; ++a)
        #pragma unroll
        for (int b = 0; b < 8; ++b) c[a][b] = 0.0f;

    int arow = tid >> 2;            // 0..63
    int acol = (tid & 3) * 4;       // 0,4,8,12
    int brow = tid >> 5;            // 0..7
    int bcol = (tid & 31) * 4;      // 0..124

    int tm = (tid >> 4) * 8;
    int tn = (tid & 15) * 8;

    for (int kt = 0; kt < KDIM / Bb_K; ++kt) {
        int k0 = kt * Bb_K;
        const float* xsrc = (k0 < DD) ? xr : xi;
        int kc = k0 & (DD - 1);

        #pragma unroll
        for (int p = 0; p < 2; ++p) {
            int r = arow + p * 64;
            float4 v = *(const float4*)&xsrc[(size_t)(bm + r) * DD + kc + acol];
            As[acol + 0][r] = v.x;
            As[acol + 1][r] = v.y;
            As[acol + 2][r] = v.z;
            As[acol + 3][r] = v.w;
        }
        #pragma unroll
        for (int p = 0; p < 2; ++p) {
            int r = brow + p * 8;
            *(float4*)&Bs[r][bcol] =
                *(const float4*)&W[(size_t)(k0 + r) * DD + bn + bcol];
        }
        __syncthreads();

        #pragma unroll
        for (int kk = 0; kk < Bb_K; ++kk) {
            float4 a0 = *(const float4*)&As[kk][tm];
            float4 a1 = *(const float4*)&As[kk][tm + 4];
            float4 b0 = *(const float4*)&Bs[kk][tn];
            float4 b1 = *(const float4*)&Bs[kk][tn + 4];
            float av[8] = {a0.x, a0.y, a0.z, a0.w, a1.x, a1.y, a1.z, a1.w};
            float bv[8] = {b0.x, b0.y, b0.z, b0.w, b1.x, b1.y, b1.z, b1.w};
            #pragma unroll
            for (int mi = 0; mi < 8; ++mi)
                #pragma unroll
                for (int ni = 0; ni < 8; ++ni)
                    c[mi][ni] += av[mi] * bv[ni];
        }
        __syncthreads();
    }

    int nb = (bn + tn) >> 3;
    #pragma unroll
    for (int mi = 0; mi < 8; ++mi) {
        float gsum = 0.0f;
        #pragma unroll
        for (int ni = 0; ni < 8; ++ni) {
            float z = (c[mi][ni] + bias[bn + tn + ni]) * 1.7015f;
            gsum += 1.0f / (1.0f + expf(-z));
        }
        float gcont = gsum * 0.125f;
        int lvl = (int)rintf(gcont * 7.0f);    // round-half-even == np.round
        lvl = min(7, max(0, lvl));
        g_levels[(size_t)(bm + tm + mi) * NN + nb] = (unsigned char)lvl;
    }
}

// ---------------------------------------------------------------------------
// Kernel C: apply U (gathered by level), blend, write bf16 interleaved with
// pair order [IMAG, REAL] per complex element (Case-I serialization).
// ---------------------------------------------------------------------------
__global__ __launch_bounds__(256)
void apply_kernel(const float* __restrict__ xr,
                  const float* __restrict__ xi,
                  unsigned short* __restrict__ out)
{
    int t = blockIdx.x * 256 + threadIdx.x;   // 0 .. B*S*N-1
    int bs = t >> 7;
    int n = t & 127;

    int L = g_levels[t];
    const float* Up = g_U + ((size_t)(L * NN + n)) * 128;
    const float* xrp = xr + (size_t)bs * DD + n * 8;
    const float* xip = xi + (size_t)bs * DD + n * 8;

    float4 r0 = *(const float4*)xrp;
    float4 r1 = *(const float4*)(xrp + 4);
    float4 i0 = *(const float4*)xip;
    float4 i1 = *(const float4*)(xip + 4);
    float xrv[8] = {r0.x, r0.y, r0.z, r0.w, r1.x, r1.y, r1.z, r1.w};
    float xiv[8] = {i0.x, i0.y, i0.z, i0.w, i1.x, i1.y, i1.z, i1.w};

    float gq = (float)L * (1.0f / 7.0f);
    float scale = gq / (gq + 1e-7f);

    unsigned int pk[8];            // 8 x (real<<16 | imag)  => [im, re] pairs
    #pragma unroll
    for (int oo = 0; oo < 8; ++oo) {
        float4 ur0 = *(const float4*)&Up[oo * 8];
        float4 ur1 = *(const float4*)&Up[oo * 8 + 4];
        float4 ui0 = *(const float4*)&Up[64 + oo * 8];
        float4 ui1 = *(const float4*)&Up[64 + oo * 8 + 4];
        float ur[8] = {ur0.x, ur0.y, ur0.z, ur0.w, ur1.x, ur1.y, ur1.z, ur1.w};
        float ui[8] = {ui0.x, ui0.y, ui0.z, ui0.w, ui1.x, ui1.y, ui1.z, ui1.w};
        float uxr = 0.0f, uxi = 0.0f;
        #pragma unroll
        for (int q = 0; q < 8; ++q) {
            uxr += ur[q] * xrv[q] - ui[q] * xiv[q];
            uxi += ur[q] * xiv[q] + ui[q] * xrv[q];
        }
        float outr = xrv[oo] + scale * (uxr - xrv[oo]);
        float outi = xiv[oo] + scale * (uxi - xiv[oo]);
        pk[oo] = bf16_bits(outi) | (bf16_bits(outr) << 16);   // [imag, real]
    }

    unsigned int* ob = (unsigned int*)(out + 2 * ((size_t)bs * DD + (size_t)n * 8));
    *(uint4*)&ob[0] = make_uint4(pk[0], pk[1], pk[2], pk[3]);
    *(uint4*)&ob[4] = make_uint4(pk[4], pk[5], pk[6], pk[7]);
}

// ---------------------------------------------------------------------------
extern "C" void kernel_launch(void* const* d_in, const int* in_sizes, int n_in,
                              void* d_out, int out_size, void* d_ws, size_t ws_size,
                              hipStream_t stream) {
    (void)in_sizes; (void)n_in; (void)out_size; (void)d_ws; (void)ws_size;
    const float* x_real = (const float*)d_in[0];
    const float* x_imag = (const float*)d_in[1];
    const float* A_real = (const float*)d_in[2];
    const float* A_imag = (const float*)d_in[3];
    const float* W_gate = (const float*)d_in[4];
    const float* b_gate = (const float*)d_in[5];
    unsigned short* out = (unsigned short*)d_out;

    hipLaunchKernelGGL(cayley_kernel, dim3(KLV * NN), dim3(256), 0, stream,
                       A_real, A_imag);
    hipLaunchKernelGGL(gate_kernel, dim3(DD / Bb_N, MM / Bb_M), dim3(256), 0, stream,
                       x_real, x_imag, W_gate, b_gate);
    hipLaunchKernelGGL(apply_kernel, dim3((MM * NN) / 256), dim3(256), 0, stream,
                       x_real, x_imag, out);
}

// Round 9
// 524.650 us; speedup vs baseline: 1.8719x; 1.8719x over previous
//
#include <hip/hip_runtime.h>
#include <hip/hip_bf16.h>
#include <math.h>

// Problem constants
#define BB 4
#define SS 4096
#define DD 1024
#define NN 128           // D / 8
#define KLV 8            // quantization levels
#define MM (BB*SS)       // 16384 rows
#define KC 2048          // x_cat width
#define KP 4096          // [hi | lo] padded width
// GEMM tiling
#define BM 128
#define BN 128
#define BK 32

typedef short bf16x8 __attribute__((ext_vector_type(8)));
typedef float f32x4 __attribute__((ext_vector_type(4)));

// Static device scratch.
__device__ float g_U[KLV * NN * 128];              // 512 KB  Cayley table
__device__ unsigned char g_levels[MM * NN];        // 2 MB    per-(token,block) level
__device__ unsigned short g_XHL[(size_t)MM * KP];  // 134 MB  [m][0..2047]=hi(x_cat), [2048..]=lo
__device__ unsigned short g_WT[(size_t)DD * KP];   // 8 MB    [n][0..2047]=wh, [2048..]=wl (W^T)

// f32 -> bf16 bits, round-to-nearest-even
__device__ __forceinline__ unsigned int bf16_bits(float f) {
    union { float f; unsigned int u; } v;
    v.f = f;
    unsigned int lsb = (v.u >> 16) & 1u;
    return (v.u + 0x7FFFu + lsb) >> 16;
}
__device__ __forceinline__ float bfbits2f(unsigned int b) {
    union { unsigned int u; float f; } v;
    v.u = b << 16;
    return v.f;
}

// async global->LDS 16B copy (lane i of wave lands at ldsbase + i*16)
__device__ __forceinline__ void gload16(const void* g, void* l) {
    __builtin_amdgcn_global_load_lds(
        (const __attribute__((address_space(1))) unsigned int*)g,
        (__attribute__((address_space(3))) unsigned int*)l, 16, 0, 0);
}

// ---------------------------------------------------------------------------
// convert_x: x_real/x_imag f32 -> g_XHL bf16 hi|lo planes.
// block = one (m, plane) row; thread t handles 4 consecutive f32.
// ---------------------------------------------------------------------------
__global__ __launch_bounds__(256)
void convert_x(const float* __restrict__ xr, const float* __restrict__ xi)
{
    int t = threadIdx.x;
    int blk = blockIdx.x;            // 0..32767
    int plane = blk & 1;
    int m = blk >> 1;
    const float* src = plane ? xi : xr;
    float4 v = *(const float4*)&src[(size_t)m * DD + t * 4];
    float f[4] = {v.x, v.y, v.z, v.w};
    unsigned int hi[4], lo[4];
    #pragma unroll
    for (int q = 0; q < 4; ++q) {
        hi[q] = bf16_bits(f[q]);
        lo[q] = bf16_bits(f[q] - bfbits2f(hi[q]));
    }
    size_t base = (size_t)m * KP + plane * DD + t * 4;
    *(uint2*)&g_XHL[base]        = make_uint2(hi[0] | (hi[1] << 16), hi[2] | (hi[3] << 16));
    *(uint2*)&g_XHL[base + 2048] = make_uint2(lo[0] | (lo[1] << 16), lo[2] | (lo[3] << 16));
}

// ---------------------------------------------------------------------------
// convert_wt: W[k][n] f32 -> g_WT[n][k] bf16 hi|lo (32x32 LDS transpose).
// ---------------------------------------------------------------------------
__global__ __launch_bounds__(256)
void convert_wt(const float* __restrict__ W)
{
    __shared__ float tile[32][33];
    int bk = (blockIdx.x >> 5) * 32;   // 64 k-tiles
    int bn = (blockIdx.x & 31) * 32;   // 32 n-tiles
    int t = threadIdx.x;

    int kk = t >> 3;                   // 0..31
    int nn4 = (t & 7) * 4;
    float4 v = *(const float4*)&W[(size_t)(bk + kk) * DD + bn + nn4];
    tile[kk][nn4 + 0] = v.x; tile[kk][nn4 + 1] = v.y;
    tile[kk][nn4 + 2] = v.z; tile[kk][nn4 + 3] = v.w;
    __syncthreads();

    int n2 = t >> 3;                   // output row (n)
    int k4 = (t & 7) * 4;
    unsigned int hi[4], lo[4];
    #pragma unroll
    for (int q = 0; q < 4; ++q) {
        float f = tile[k4 + q][n2];
        hi[q] = bf16_bits(f);
        lo[q] = bf16_bits(f - bfbits2f(hi[q]));
    }
    size_t base = (size_t)(bn + n2) * KP + bk + k4;
    *(uint2*)&g_WT[base]        = make_uint2(hi[0] | (hi[1] << 16), hi[2] | (hi[3] << 16));
    *(uint2*)&g_WT[base + 2048] = make_uint2(lo[0] | (lo[1] << 16), lo[2] | (lo[3] << 16));
}

// ---------------------------------------------------------------------------
// Kernel A: Cayley table (Gauss-Jordan, 16x16 augmented, no pivoting).
// ---------------------------------------------------------------------------
__global__ __launch_bounds__(256)
void cayley_kernel(const float* __restrict__ A_real,
                   const float* __restrict__ A_imag)
{
    int idx = blockIdx.x;            // 0..1023  = L*128 + n
    int L = idx >> 7;
    int n = idx & 127;
    float g = (float)L * (1.0f / 7.0f);

    __shared__ float M[16][34];

    int tid = threadIdx.x;
    int i = tid >> 4;
    int j = tid & 15;

    const float* Ar = A_real + n * 64;
    const float* Ai = A_imag + n * 64;
    int bi = i >> 3;
    int ii = i & 7, jj = j & 7;

    float ar = (Ar[ii * 8 + jj] - Ar[jj * 8 + ii]) * 0.5f * g;
    float ai = (Ai[ii * 8 + jj] + Ai[jj * 8 + ii]) * 0.5f * g;
    float eye = (ii == jj) ? 1.0f : 0.0f;

    int bj = j >> 3;
    float lhs, rhs;
    if (bi == bj) { lhs = eye + ar; rhs = eye - ar; }
    else if (bi == 0) { lhs = -ai; rhs = ai; }
    else { lhs = ai; rhs = -ai; }

    M[i][j] = lhs;
    M[i][16 + j] = rhs;
    __syncthreads();

    for (int k = 0; k < 16; ++k) {
        float f = M[i][k] / M[k][k];
        __syncthreads();
        if (i != k) {
            M[i][j]      -= f * M[k][j];
            M[i][16 + j] -= f * M[k][16 + j];
        }
        __syncthreads();
    }

    float x = M[i][16 + j] / M[i][i];
    if (j < 8) {
        g_U[(size_t)idx * 128 + bi * 64 + ii * 8 + j] = x;
    }
}

// ---------------------------------------------------------------------------
// gate_mfma: split-bf16 MFMA GEMM (logical K = 3x2048) fused with
// sigmoid + 8-col mean + quantize -> g_levels.
// m97 structure: 128x128 tile, BK=32, 4 waves, gload_lds staging,
// seg-XOR swizzle both sides, XCD-aware block mapping.
// ---------------------------------------------------------------------------
__global__ __launch_bounds__(256, 4)
void gate_mfma(const float* __restrict__ bias)
{
    __shared__ __align__(16) unsigned short As[BM * BK];
    __shared__ __align__(16) unsigned short Bs[BN * BK];

    int tid = threadIdx.x;
    int raw = blockIdx.x;              // 0..1023
    int xcd = raw & 7;
    int loc = raw >> 3;                // 0..127
    int mt = (xcd << 4) | (loc >> 3);  // 0..127  (16 m-strips per XCD)
    int nt = loc & 7;                  // 0..7
    int bm = mt * BM, bn = nt * BN;

    int lane = tid & 63;
    int wv = tid >> 6;
    int wr = wv >> 1, wc = wv & 1;     // 2x2 waves, 64x64 each
    int r16 = lane & 15, sgrp = lane >> 4;

    f32x4 acc[4][4];
    #pragma unroll
    for (int a = 0; a < 4; ++a)
        #pragma unroll
        for (int b = 0; b < 4; ++b) {
            f32x4 z = {0.0f, 0.0f, 0.0f, 0.0f};
            acc[a][b] = z;
        }

    for (int c = 0; c < KC / BK; ++c) {       // 64 K-chunks
        int c32 = c * BK;
        #pragma unroll
        for (int term = 0; term < 3; ++term) {
            int acol = (term == 1) ? 2048 + c32 : c32;   // xl for term1 else xh
            int bcol = (term == 2) ? 2048 + c32 : c32;   // wl for term2 else wh

            // stage 512+512 chunks of 16B (A,B), linear LDS dest, swizzled src
            #pragma unroll
            for (int h = 0; h < 2; ++h) {
                int ck = h * 256 + tid;
                int m = ck >> 2, sl = ck & 3;
                int sw = (m & 3) ^ ((m >> 2) & 3);
                int seg = sl ^ sw;
                gload16(&g_XHL[(size_t)(bm + m) * KP + acol + seg * 8], &As[ck * 8]);
                gload16(&g_WT [(size_t)(bn + m) * KP + bcol + seg * 8], &Bs[ck * 8]);
            }
            __syncthreads();

            bf16x8 aF[4], bF[4];
            #pragma unroll
            for (int mi = 0; mi < 4; ++mi) {
                int row = wr * 64 + mi * 16 + r16;
                int sw = (row & 3) ^ ((row >> 2) & 3);
                aF[mi] = *(const bf16x8*)&As[row * BK + ((sgrp ^ sw) & 3) * 8];
            }
            #pragma unroll
            for (int ni = 0; ni < 4; ++ni) {
                int row = wc * 64 + ni * 16 + r16;
                int sw = (row & 3) ^ ((row >> 2) & 3);
                bF[ni] = *(const bf16x8*)&Bs[row * BK + ((sgrp ^ sw) & 3) * 8];
            }
            #pragma unroll
            for (int mi = 0; mi < 4; ++mi)
                #pragma unroll
                for (int ni = 0; ni < 4; ++ni)
                    acc[mi][ni] = __builtin_amdgcn_mfma_f32_16x16x32_bf16(
                        aF[mi], bF[ni], acc[mi][ni], 0, 0, 0);
            __syncthreads();
        }
    }

    // Epilogue: z = (c + bias)*1.7015 -> sigmoid -> mean over 8 cols -> level
    #pragma unroll
    for (int mi = 0; mi < 4; ++mi) {
        #pragma unroll
        for (int ni = 0; ni < 4; ++ni) {
            int n = bn + wc * 64 + ni * 16 + r16;
            float bb = bias[n];
            #pragma unroll
            for (int r = 0; r < 4; ++r) {
                float z = (acc[mi][ni][r] + bb) * 1.7015f;
                float s = 1.0f / (1.0f + expf(-z));
                s += __shfl_xor(s, 1);
                s += __shfl_xor(s, 2);
                s += __shfl_xor(s, 4);
                if ((lane & 7) == 0) {
                    float gcont = s * 0.125f;
                    int lvl = (int)rintf(gcont * 7.0f);
                    lvl = min(7, max(0, lvl));
                    int m = bm + wr * 64 + mi * 16 + sgrp * 4 + r;
                    g_levels[(size_t)m * NN + (n >> 3)] = (unsigned char)lvl;
                }
            }
        }
    }
}

// ---------------------------------------------------------------------------
// apply: gather U by level, rotate, blend, write bf16 pairs [imag, real].
// ---------------------------------------------------------------------------
__global__ __launch_bounds__(256)
void apply_kernel(const float* __restrict__ xr,
                  const float* __restrict__ xi,
                  unsigned short* __restrict__ out)
{
    int t = blockIdx.x * 256 + threadIdx.x;   // 0 .. B*S*N-1
    int bs = t >> 7;
    int n = t & 127;

    int L = g_levels[t];
    const float* Up = g_U + ((size_t)(L * NN + n)) * 128;
    const float* xrp = xr + (size_t)bs * DD + n * 8;
    const float* xip = xi + (size_t)bs * DD + n * 8;

    float4 r0 = *(const float4*)xrp;
    float4 r1 = *(const float4*)(xrp + 4);
    float4 i0 = *(const float4*)xip;
    float4 i1 = *(const float4*)(xip + 4);
    float xrv[8] = {r0.x, r0.y, r0.z, r0.w, r1.x, r1.y, r1.z, r1.w};
    float xiv[8] = {i0.x, i0.y, i0.z, i0.w, i1.x, i1.y, i1.z, i1.w};

    float gq = (float)L * (1.0f / 7.0f);
    float scale = gq / (gq + 1e-7f);

    unsigned int pk[8];            // 8 x (real<<16 | imag) => [im, re] pairs
    #pragma unroll
    for (int oo = 0; oo < 8; ++oo) {
        float4 ur0 = *(const float4*)&Up[oo * 8];
        float4 ur1 = *(const float4*)&Up[oo * 8 + 4];
        float4 ui0 = *(const float4*)&Up[64 + oo * 8];
        float4 ui1 = *(const float4*)&Up[64 + oo * 8 + 4];
        float ur[8] = {ur0.x, ur0.y, ur0.z, ur0.w, ur1.x, ur1.y, ur1.z, ur1.w};
        float ui[8] = {ui0.x, ui0.y, ui0.z, ui0.w, ui1.x, ui1.y, ui1.z, ui1.w};
        float uxr = 0.0f, uxi = 0.0f;
        #pragma unroll
        for (int q = 0; q < 8; ++q) {
            uxr += ur[q] * xrv[q] - ui[q] * xiv[q];
            uxi += ur[q] * xiv[q] + ui[q] * xrv[q];
        }
        float outr = xrv[oo] + scale * (uxr - xrv[oo]);
        float outi = xiv[oo] + scale * (uxi - xiv[oo]);
        pk[oo] = bf16_bits(outi) | (bf16_bits(outr) << 16);   // [imag, real]
    }

    unsigned int* ob = (unsigned int*)(out + 2 * ((size_t)bs * DD + (size_t)n * 8));
    *(uint4*)&ob[0] = make_uint4(pk[0], pk[1], pk[2], pk[3]);
    *(uint4*)&ob[4] = make_uint4(pk[4], pk[5], pk[6], pk[7]);
}

// ---------------------------------------------------------------------------
extern "C" void kernel_launch(void* const* d_in, const int* in_sizes, int n_in,
                              void* d_out, int out_size, void* d_ws, size_t ws_size,
                              hipStream_t stream) {
    (void)in_sizes; (void)n_in; (void)out_size; (void)d_ws; (void)ws_size;
    const float* x_real = (const float*)d_in[0];
    const float* x_imag = (const float*)d_in[1];
    const float* A_real = (const float*)d_in[2];
    const float* A_imag = (const float*)d_in[3];
    const float* W_gate = (const float*)d_in[4];
    const float* b_gate = (const float*)d_in[5];
    unsigned short* out = (unsigned short*)d_out;

    hipLaunchKernelGGL(convert_x, dim3(2 * MM), dim3(256), 0, stream, x_real, x_imag);
    hipLaunchKernelGGL(convert_wt, dim3(64 * 32), dim3(256), 0, stream, W_gate);
    hipLaunchKernelGGL(cayley_kernel, dim3(KLV * NN), dim3(256), 0, stream,
                       A_real, A_imag);
    hipLaunchKernelGGL(gate_mfma, dim3((MM / BM) * (DD / BN)), dim3(256), 0, stream,
                       b_gate);
    hipLaunchKernelGGL(apply_kernel, dim3((MM * NN) / 256), dim3(256), 0, stream,
                       x_real, x_imag, out);
}

// Round 10
// 397.540 us; speedup vs baseline: 2.4705x; 1.3197x over previous
//
#include <hip/hip_runtime.h>
#include <hip/hip_bf16.h>
#include <math.h>

// Problem constants
#define BB 4
#define SS 4096
#define DD 1024
#define NN 128           // D / 8
#define KLV 8            // quantization levels
#define MM (BB*SS)       // 16384 rows
#define KC 2048          // x_cat width
#define KP 4096          // [hi | lo] padded width
#define NT 96            // virtual K tiles: 3 terms x 32 chunks of 64

typedef short bf16x8 __attribute__((ext_vector_type(8)));
typedef float f32x4 __attribute__((ext_vector_type(4)));

// Static device scratch.
__device__ float g_U[KLV * NN * 128];              // 512 KB  Cayley table
__device__ unsigned char g_levels[MM * NN];        // 2 MB    per-(token,block) level
__device__ unsigned short g_XHL[(size_t)MM * KP];  // 134 MB  [m][0..2047]=hi(x_cat), [2048..]=lo
__device__ unsigned short g_WT[(size_t)DD * KP];   // 8 MB    [n][0..2047]=wh, [2048..]=wl (W^T)

// f32 -> bf16 bits, round-to-nearest-even
__device__ __forceinline__ unsigned int bf16_bits(float f) {
    union { float f; unsigned int u; } v;
    v.f = f;
    unsigned int lsb = (v.u >> 16) & 1u;
    return (v.u + 0x7FFFu + lsb) >> 16;
}
__device__ __forceinline__ float bfbits2f(unsigned int b) {
    union { unsigned int u; float f; } v;
    v.u = b << 16;
    return v.f;
}

// async global->LDS 16B copy
__device__ __forceinline__ void gload16(const void* g, void* l) {
    __builtin_amdgcn_global_load_lds(
        (const __attribute__((address_space(1))) unsigned int*)g,
        (__attribute__((address_space(3))) unsigned int*)l, 16, 0, 0);
}

// ---------------------------------------------------------------------------
// convert_x: x_real/x_imag f32 -> g_XHL bf16 hi|lo planes.
// ---------------------------------------------------------------------------
__global__ __launch_bounds__(256)
void convert_x(const float* __restrict__ xr, const float* __restrict__ xi)
{
    int t = threadIdx.x;
    int blk = blockIdx.x;            // 0..32767
    int plane = blk & 1;
    int m = blk >> 1;
    const float* src = plane ? xi : xr;
    float4 v = *(const float4*)&src[(size_t)m * DD + t * 4];
    float f[4] = {v.x, v.y, v.z, v.w};
    unsigned int hi[4], lo[4];
    #pragma unroll
    for (int q = 0; q < 4; ++q) {
        hi[q] = bf16_bits(f[q]);
        lo[q] = bf16_bits(f[q] - bfbits2f(hi[q]));
    }
    size_t base = (size_t)m * KP + plane * DD + t * 4;
    *(uint2*)&g_XHL[base]        = make_uint2(hi[0] | (hi[1] << 16), hi[2] | (hi[3] << 16));
    *(uint2*)&g_XHL[base + 2048] = make_uint2(lo[0] | (lo[1] << 16), lo[2] | (lo[3] << 16));
}

// ---------------------------------------------------------------------------
// convert_wt: W[k][n] f32 -> g_WT[n][k] bf16 hi|lo (32x32 LDS transpose).
// ---------------------------------------------------------------------------
__global__ __launch_bounds__(256)
void convert_wt(const float* __restrict__ W)
{
    __shared__ float tile[32][33];
    int bk = (blockIdx.x >> 5) * 32;
    int bn = (blockIdx.x & 31) * 32;
    int t = threadIdx.x;

    int kk = t >> 3;
    int nn4 = (t & 7) * 4;
    float4 v = *(const float4*)&W[(size_t)(bk + kk) * DD + bn + nn4];
    tile[kk][nn4 + 0] = v.x; tile[kk][nn4 + 1] = v.y;
    tile[kk][nn4 + 2] = v.z; tile[kk][nn4 + 3] = v.w;
    __syncthreads();

    int n2 = t >> 3;
    int k4 = (t & 7) * 4;
    unsigned int hi[4], lo[4];
    #pragma unroll
    for (int q = 0; q < 4; ++q) {
        float f = tile[k4 + q][n2];
        hi[q] = bf16_bits(f);
        lo[q] = bf16_bits(f - bfbits2f(hi[q]));
    }
    size_t base = (size_t)(bn + n2) * KP + bk + k4;
    *(uint2*)&g_WT[base]        = make_uint2(hi[0] | (hi[1] << 16), hi[2] | (hi[3] << 16));
    *(uint2*)&g_WT[base + 2048] = make_uint2(lo[0] | (lo[1] << 16), lo[2] | (lo[3] << 16));
}

// ---------------------------------------------------------------------------
// cayley_kernel: Gauss-Jordan on 16x16 augmented system.
// ---------------------------------------------------------------------------
__global__ __launch_bounds__(256)
void cayley_kernel(const float* __restrict__ A_real,
                   const float* __restrict__ A_imag)
{
    int idx = blockIdx.x;
    int L = idx >> 7;
    int n = idx & 127;
    float g = (float)L * (1.0f / 7.0f);

    __shared__ float M[16][34];

    int tid = threadIdx.x;
    int i = tid >> 4;
    int j = tid & 15;

    const float* Ar = A_real + n * 64;
    const float* Ai = A_imag + n * 64;
    int bi = i >> 3;
    int ii = i & 7, jj = j & 7;

    float ar = (Ar[ii * 8 + jj] - Ar[jj * 8 + ii]) * 0.5f * g;
    float ai = (Ai[ii * 8 + jj] + Ai[jj * 8 + ii]) * 0.5f * g;
    float eye = (ii == jj) ? 1.0f : 0.0f;

    int bj = j >> 3;
    float lhs, rhs;
    if (bi == bj) { lhs = eye + ar; rhs = eye - ar; }
    else if (bi == 0) { lhs = -ai; rhs = ai; }
    else { lhs = ai; rhs = -ai; }

    M[i][j] = lhs;
    M[i][16 + j] = rhs;
    __syncthreads();

    for (int k = 0; k < 16; ++k) {
        float f = M[i][k] / M[k][k];
        __syncthreads();
        if (i != k) {
            M[i][j]      -= f * M[k][j];
            M[i][16 + j] -= f * M[k][16 + j];
        }
        __syncthreads();
    }

    float x = M[i][16 + j] / M[i][i];
    if (j < 8) {
        g_U[(size_t)idx * 128 + bi * 64 + ii * 8 + j] = x;
    }
}

// ---------------------------------------------------------------------------
// gate_mfma8: 256x256 tile, BK=64, 8 waves, 8-phase counted-vmcnt schedule
// (T1 XCD-map + T2 XOR swizzle + T3/T4 pipeline + T5 setprio).
// Virtual K = 96 tiles: chunk=kt/3, term=kt%3 (xh*wh, xl*wh, xh*wl).
// ---------------------------------------------------------------------------
__device__ __forceinline__ int colsA_of(int kt) {
    int k = (kt < NT) ? kt : 0;
    int ch = k / 3, tm = k - 3 * ch;
    return ch * 64 + (tm == 1 ? 2048 : 0);
}
__device__ __forceinline__ int colsB_of(int kt) {
    int k = (kt < NT) ? kt : 0;
    int ch = k / 3, tm = k - 3 * ch;
    return ch * 64 + (tm == 2 ? 2048 : 0);
}

__global__ __launch_bounds__(512, 1)
void gate_mfma8(const float* __restrict__ bias)
{
    __shared__ __align__(16) unsigned short lds[65536];   // 128 KB: 2 bufs x (A 16K + B 16K shorts)

    const int tid = threadIdx.x;
    const int bid = blockIdx.x;          // 0..255
    const int xcd = bid & 7;
    const int loc = bid >> 3;            // 0..31
    const int nt = xcd & 3;              // 1 n-tile per XCD-pair: WT slice 2MB fits L2
    const int mt = (xcd >> 2) * 32 + loc;
    const int bm = mt * 256, bn = nt * 256;

    const int lane = tid & 63;
    const int wv = tid >> 6;             // 8 waves: 2M x 4N
    const int wr = wv >> 2;              // 0..1
    const int wc = wv & 3;               // 0..3
    const int r16 = lane & 15, sgrp = lane >> 4;

    f32x4 acc[8][4];
    #pragma unroll
    for (int a = 0; a < 8; ++a)
        #pragma unroll
        for (int b = 0; b < 4; ++b) {
            f32x4 z = {0.0f, 0.0f, 0.0f, 0.0f};
            acc[a][b] = z;
        }

    // STAGE one half-tile (128 rows x 64 cols bf16 = 16KB): 2 gloads/thread.
    // Linear LDS dest; source col-unit pre-swizzled by ^(row&7)  [rule 21].
    #define STAGE(cbuf, isB, half, colbase, rowbase)                              \
    {                                                                             \
        const unsigned short* gsrc_ = (isB) ? g_WT : g_XHL;                       \
        _Pragma("unroll")                                                         \
        for (int h2 = 0; h2 < 2; ++h2) {                                          \
            int ck = h2 * 512 + tid;                                              \
            int row = ck >> 3, unit = ck & 7;                                     \
            int su = unit ^ (row & 7);                                            \
            gload16(&gsrc_[(size_t)((rowbase) + (half) * 128 + row) * KP          \
                           + (colbase) + su * 8],                                 \
                    &lds[(cbuf) * 32768 + (isB) * 16384 + (half) * 8192 + ck * 8]);\
        }                                                                         \
    }

    // Prologue: tile0 fully + tile1 B; wait all but last 2 stages (4 loads).
    STAGE(0, 0, 0, colsA_of(0), bm); STAGE(0, 0, 1, colsA_of(0), bm);
    STAGE(0, 1, 0, colsB_of(0), bn); STAGE(0, 1, 1, colsB_of(0), bn);
    STAGE(1, 1, 0, colsB_of(1), bn); STAGE(1, 1, 1, colsB_of(1), bn);
    asm volatile("s_waitcnt vmcnt(4)" ::: "memory");
    __builtin_amdgcn_s_barrier();

    for (int kt = 0; kt < NT; ++kt) {
        const int cur = kt & 1;
        const int nxt = cur ^ 1;
        unsigned short* Abuf = &lds[cur * 32768];
        unsigned short* Bbuf = &lds[cur * 32768 + 16384];
        const int cA1 = colsA_of(kt + 1);
        const int cB2 = colsB_of(kt + 2);

        bf16x8 bf[4][2];
        #pragma unroll
        for (int q = 0; q < 4; ++q) {
            if (q == 0) {
                #pragma unroll
                for (int ni = 0; ni < 4; ++ni)
                    #pragma unroll
                    for (int kk = 0; kk < 2; ++kk) {
                        int row = wc * 64 + ni * 16 + r16;
                        int u = kk * 4 + sgrp;
                        bf[ni][kk] = *(const bf16x8*)&Bbuf[row * 64 + (u ^ (row & 7)) * 8];
                    }
            }
            bf16x8 af[2][2];
            #pragma unroll
            for (int dm = 0; dm < 2; ++dm)
                #pragma unroll
                for (int kk = 0; kk < 2; ++kk) {
                    int row = wr * 128 + (q * 2 + dm) * 16 + r16;
                    int u = kk * 4 + sgrp;
                    af[dm][kk] = *(const bf16x8*)&Abuf[row * 64 + (u ^ (row & 7)) * 8];
                }
            // Prefetch schedule: t+1.A0, t+1.A1, t+2.B0, t+2.B1.
            // (cur B overwrite legal: all waves' B reads done by q0's barrier.)
            if (q == 0)      { STAGE(nxt, 0, 0, cA1, bm); }
            else if (q == 1) { STAGE(nxt, 0, 1, cA1, bm); }
            else if (q == 2) { STAGE(cur, 1, 0, cB2, bn); }
            else             { STAGE(cur, 1, 1, cB2, bn); }
            __builtin_amdgcn_s_barrier();
            __builtin_amdgcn_s_setprio(1);
            #pragma unroll
            for (int dm = 0; dm < 2; ++dm)
                #pragma unroll
                for (int ni = 0; ni < 4; ++ni)
                    #pragma unroll
                    for (int kk = 0; kk < 2; ++kk)
                        acc[q * 2 + dm][ni] = __builtin_amdgcn_mfma_f32_16x16x32_bf16(
                            af[dm][kk], bf[ni][kk], acc[q * 2 + dm][ni], 0, 0, 0);
            __builtin_amdgcn_s_setprio(0);
            __builtin_amdgcn_s_barrier();
        }
        // Checkpoint: allow q2,q3's stages (4 loads) in flight; t+1 fully landed.
        asm volatile("s_waitcnt vmcnt(4)" ::: "memory");
    }
    asm volatile("s_waitcnt vmcnt(0)" ::: "memory");
    #undef STAGE

    // Epilogue: z = (c + bias)*1.7015 -> sigmoid -> mean over 8 cols -> level
    #pragma unroll
    for (int mi = 0; mi < 8; ++mi) {
        #pragma unroll
        for (int ni = 0; ni < 4; ++ni) {
            int n = bn + wc * 64 + ni * 16 + r16;
            float bb = bias[n];
            #pragma unroll
            for (int r = 0; r < 4; ++r) {
                float z = (acc[mi][ni][r] + bb) * 1.7015f;
                float s = 1.0f / (1.0f + expf(-z));
                s += __shfl_xor(s, 1);
                s += __shfl_xor(s, 2);
                s += __shfl_xor(s, 4);
                if ((lane & 7) == 0) {
                    float gcont = s * 0.125f;
                    int lvl = (int)rintf(gcont * 7.0f);
                    lvl = min(7, max(0, lvl));
                    int m = bm + wr * 128 + mi * 16 + sgrp * 4 + r;
                    g_levels[(size_t)m * NN + (n >> 3)] = (unsigned char)lvl;
                }
            }
        }
    }
}

// ---------------------------------------------------------------------------
// apply: gather U by level, rotate, blend, write bf16 pairs [imag, real].
// ---------------------------------------------------------------------------
__global__ __launch_bounds__(256)
void apply_kernel(const float* __restrict__ xr,
                  const float* __restrict__ xi,
                  unsigned short* __restrict__ out)
{
    int t = blockIdx.x * 256 + threadIdx.x;
    int bs = t >> 7;
    int n = t & 127;

    int L = g_levels[t];
    const float* Up = g_U + ((size_t)(L * NN + n)) * 128;
    const float* xrp = xr + (size_t)bs * DD + n * 8;
    const float* xip = xi + (size_t)bs * DD + n * 8;

    float4 r0 = *(const float4*)xrp;
    float4 r1 = *(const float4*)(xrp + 4);
    float4 i0 = *(const float4*)xip;
    float4 i1 = *(const float4*)(xip + 4);
    float xrv[8] = {r0.x, r0.y, r0.z, r0.w, r1.x, r1.y, r1.z, r1.w};
    float xiv[8] = {i0.x, i0.y, i0.z, i0.w, i1.x, i1.y, i1.z, i1.w};

    float gq = (float)L * (1.0f / 7.0f);
    float scale = gq / (gq + 1e-7f);

    unsigned int pk[8];
    #pragma unroll
    for (int oo = 0; oo < 8; ++oo) {
        float4 ur0 = *(const float4*)&Up[oo * 8];
        float4 ur1 = *(const float4*)&Up[oo * 8 + 4];
        float4 ui0 = *(const float4*)&Up[64 + oo * 8];
        float4 ui1 = *(const float4*)&Up[64 + oo * 8 + 4];
        float ur[8] = {ur0.x, ur0.y, ur0.z, ur0.w, ur1.x, ur1.y, ur1.z, ur1.w};
        float ui[8] = {ui0.x, ui0.y, ui0.z, ui0.w, ui1.x, ui1.y, ui1.z, ui1.w};
        float uxr = 0.0f, uxi = 0.0f;
        #pragma unroll
        for (int q = 0; q < 8; ++q) {
            uxr += ur[q] * xrv[q] - ui[q] * xiv[q];
            uxi += ur[q] * xiv[q] + ui[q] * xrv[q];
        }
        float outr = xrv[oo] + scale * (uxr - xrv[oo]);
        float outi = xiv[oo] + scale * (uxi - xiv[oo]);
        pk[oo] = bf16_bits(outi) | (bf16_bits(outr) << 16);   // [imag, real]
    }

    unsigned int* ob = (unsigned int*)(out + 2 * ((size_t)bs * DD + (size_t)n * 8));
    *(uint4*)&ob[0] = make_uint4(pk[0], pk[1], pk[2], pk[3]);
    *(uint4*)&ob[4] = make_uint4(pk[4], pk[5], pk[6], pk[7]);
}

// ---------------------------------------------------------------------------
extern "C" void kernel_launch(void* const* d_in, const int* in_sizes, int n_in,
                              void* d_out, int out_size, void* d_ws, size_t ws_size,
                              hipStream_t stream) {
    (void)in_sizes; (void)n_in; (void)out_size; (void)d_ws; (void)ws_size;
    const float* x_real = (const float*)d_in[0];
    const float* x_imag = (const float*)d_in[1];
    const float* A_real = (const float*)d_in[2];
    const float* A_imag = (const float*)d_in[3];
    const float* W_gate = (const float*)d_in[4];
    const float* b_gate = (const float*)d_in[5];
    unsigned short* out = (unsigned short*)d_out;

    hipLaunchKernelGGL(convert_x, dim3(2 * MM), dim3(256), 0, stream, x_real, x_imag);
    hipLaunchKernelGGL(convert_wt, dim3(64 * 32), dim3(256), 0, stream, W_gate);
    hipLaunchKernelGGL(cayley_kernel, dim3(KLV * NN), dim3(256), 0, stream,
                       A_real, A_imag);
    hipLaunchKernelGGL(gate_mfma8, dim3(256), dim3(512), 0, stream, b_gate);
    hipLaunchKernelGGL(apply_kernel, dim3((MM * NN) / 256), dim3(256), 0, stream,
                       x_real, x_imag, out);
}

// Round 11
// 393.171 us; speedup vs baseline: 2.4979x; 1.0111x over previous
//
#include <hip/hip_runtime.h>
#include <hip/hip_bf16.h>
#include <math.h>

// Problem constants
#define BB 4
#define SS 4096
#define DD 1024
#define NN 128           // D / 8
#define KLV 8            // quantization levels
#define MM (BB*SS)       // 16384 rows
#define KC 2048          // x_cat width
#define KP 4096          // [hi | lo] padded width
#define NT 96            // virtual K tiles: 3 terms x 32 chunks of 64

typedef short bf16x8 __attribute__((ext_vector_type(8)));
typedef float f32x4 __attribute__((ext_vector_type(4)));

// Static device scratch.
__device__ float g_U[KLV * NN * 128];              // 512 KB  Cayley table
__device__ unsigned char g_levels[MM * NN];        // 2 MB    per-(token,block) level
__device__ unsigned short g_XHL[(size_t)MM * KP];  // 134 MB  [m][0..2047]=hi(x_cat), [2048..]=lo
__device__ unsigned short g_WT[(size_t)DD * KP];   // 8 MB    [n][0..2047]=wh, [2048..]=wl (W^T)

// f32 -> bf16 bits, round-to-nearest-even
__device__ __forceinline__ unsigned int bf16_bits(float f) {
    union { float f; unsigned int u; } v;
    v.f = f;
    unsigned int lsb = (v.u >> 16) & 1u;
    return (v.u + 0x7FFFu + lsb) >> 16;
}
__device__ __forceinline__ float bfbits2f(unsigned int b) {
    union { unsigned int u; float f; } v;
    v.u = b << 16;
    return v.f;
}

// async global->LDS 16B copy
__device__ __forceinline__ void gload16(const void* g, void* l) {
    __builtin_amdgcn_global_load_lds(
        (const __attribute__((address_space(1))) unsigned int*)g,
        (__attribute__((address_space(3))) unsigned int*)l, 16, 0, 0);
}

// ---------------------------------------------------------------------------
// prep_kernel: fused {convert_x | convert_wt | cayley} by blockIdx range.
// All three are independent (disjoint outputs, input-only reads).
// ---------------------------------------------------------------------------
#define WT_BLOCKS (64 * 32)
__global__ __launch_bounds__(256)
void prep_kernel(const float* __restrict__ xr, const float* __restrict__ xi,
                 const float* __restrict__ W,
                 const float* __restrict__ A_real,
                 const float* __restrict__ A_imag)
{
    __shared__ __align__(16) float sh[33 * 32];   // wt: tile[32][33]; cayley: M[16][34]
    int blk = blockIdx.x;
    int t = threadIdx.x;

    if (blk < 2 * MM) {
        // ---- convert_x: x f32 -> bf16 hi|lo planes ----
        int plane = blk & 1;
        int m = blk >> 1;
        const float* src = plane ? xi : xr;
        float4 v = *(const float4*)&src[(size_t)m * DD + t * 4];
        float f[4] = {v.x, v.y, v.z, v.w};
        unsigned int hi[4], lo[4];
        #pragma unroll
        for (int q = 0; q < 4; ++q) {
            hi[q] = bf16_bits(f[q]);
            lo[q] = bf16_bits(f[q] - bfbits2f(hi[q]));
        }
        size_t base = (size_t)m * KP + plane * DD + t * 4;
        *(uint2*)&g_XHL[base]        = make_uint2(hi[0] | (hi[1] << 16), hi[2] | (hi[3] << 16));
        *(uint2*)&g_XHL[base + 2048] = make_uint2(lo[0] | (lo[1] << 16), lo[2] | (lo[3] << 16));
        return;
    }
    blk -= 2 * MM;

    if (blk < WT_BLOCKS) {
        // ---- convert_wt: W[k][n] -> g_WT[n][k] bf16 hi|lo (32x32 transpose) ----
        float (*tile)[33] = (float(*)[33])sh;
        int bk = (blk >> 5) * 32;
        int bn = (blk & 31) * 32;

        int kk = t >> 3;
        int nn4 = (t & 7) * 4;
        float4 v = *(const float4*)&W[(size_t)(bk + kk) * DD + bn + nn4];
        tile[kk][nn4 + 0] = v.x; tile[kk][nn4 + 1] = v.y;
        tile[kk][nn4 + 2] = v.z; tile[kk][nn4 + 3] = v.w;
        __syncthreads();

        int n2 = t >> 3;
        int k4 = (t & 7) * 4;
        unsigned int hi[4], lo[4];
        #pragma unroll
        for (int q = 0; q < 4; ++q) {
            float f = tile[k4 + q][n2];
            hi[q] = bf16_bits(f);
            lo[q] = bf16_bits(f - bfbits2f(hi[q]));
        }
        size_t base = (size_t)(bn + n2) * KP + bk + k4;
        *(uint2*)&g_WT[base]        = make_uint2(hi[0] | (hi[1] << 16), hi[2] | (hi[3] << 16));
        *(uint2*)&g_WT[base + 2048] = make_uint2(lo[0] | (lo[1] << 16), lo[2] | (lo[3] << 16));
        return;
    }
    blk -= WT_BLOCKS;

    {
        // ---- cayley: Gauss-Jordan on 16x16 augmented system ----
        float (*M)[34] = (float(*)[34])sh;
        int L = blk >> 7;
        int n = blk & 127;
        float g = (float)L * (1.0f / 7.0f);

        int i = t >> 4;
        int j = t & 15;

        const float* Ar = A_real + n * 64;
        const float* Ai = A_imag + n * 64;
        int bi = i >> 3;
        int ii = i & 7, jj = j & 7;

        float ar = (Ar[ii * 8 + jj] - Ar[jj * 8 + ii]) * 0.5f * g;
        float ai = (Ai[ii * 8 + jj] + Ai[jj * 8 + ii]) * 0.5f * g;
        float eye = (ii == jj) ? 1.0f : 0.0f;

        int bj = j >> 3;
        float lhs, rhs;
        if (bi == bj) { lhs = eye + ar; rhs = eye - ar; }
        else if (bi == 0) { lhs = -ai; rhs = ai; }
        else { lhs = ai; rhs = -ai; }

        M[i][j] = lhs;
        M[i][16 + j] = rhs;
        __syncthreads();

        for (int k = 0; k < 16; ++k) {
            float f = M[i][k] / M[k][k];
            __syncthreads();
            if (i != k) {
                M[i][j]      -= f * M[k][j];
                M[i][16 + j] -= f * M[k][16 + j];
            }
            __syncthreads();
        }

        float x = M[i][16 + j] / M[i][i];
        if (j < 8) {
            g_U[(size_t)blk * 128 + bi * 64 + ii * 8 + j] = x;
        }
    }
}

// ---------------------------------------------------------------------------
// gate_mfma8: 256x256 tile, BK=64, 8 waves, 8-phase counted-vmcnt schedule.
// XCD map v2: 4 n-tiles of each m-strip co-resident on ONE XCD so the
// A-strip is fetched once into that XCD's L2 (fix for 4x A over-fetch).
// Virtual K = 96 tiles: chunk=kt/3, term=kt%3 (xh*wh, xl*wh, xh*wl).
// ---------------------------------------------------------------------------
__device__ __forceinline__ int colsA_of(int kt) {
    int k = (kt < NT) ? kt : 0;
    int ch = k / 3, tm = k - 3 * ch;
    return ch * 64 + (tm == 1 ? 2048 : 0);
}
__device__ __forceinline__ int colsB_of(int kt) {
    int k = (kt < NT) ? kt : 0;
    int ch = k / 3, tm = k - 3 * ch;
    return ch * 64 + (tm == 2 ? 2048 : 0);
}

__global__ __launch_bounds__(512, 1)
void gate_mfma8(const float* __restrict__ bias)
{
    __shared__ __align__(16) unsigned short lds[65536];   // 128 KB: 2 bufs x (A 16K + B 16K shorts)

    const int tid = threadIdx.x;
    const int bid = blockIdx.x;          // 0..255
    // Dispatch round-robins bid%8 across XCDs [m09]; keep an m-strip's 4
    // n-tiles on one XCD (consecutive bid>>3 values, same bid&7).
    const int xcd = bid & 7;
    const int grp = bid >> 3;            // 0..31
    const int mt = xcd * 8 + (grp >> 2); // 0..63, 8 strips per XCD
    const int nt = grp & 3;              // 4 n-tiles, same XCD as their m-strip
    const int bm = mt * 256, bn = nt * 256;

    const int lane = tid & 63;
    const int wv = tid >> 6;             // 8 waves: 2M x 4N
    const int wr = wv >> 2;              // 0..1
    const int wc = wv & 3;               // 0..3
    const int r16 = lane & 15, sgrp = lane >> 4;

    f32x4 acc[8][4];
    #pragma unroll
    for (int a = 0; a < 8; ++a)
        #pragma unroll
        for (int b = 0; b < 4; ++b) {
            f32x4 z = {0.0f, 0.0f, 0.0f, 0.0f};
            acc[a][b] = z;
        }

    // STAGE one half-tile (128 rows x 64 cols bf16 = 16KB): 2 gloads/thread.
    // Linear LDS dest; source col-unit pre-swizzled by ^(row&7)  [rule 21].
    #define STAGE(cbuf, isB, half, colbase, rowbase)                              \
    {                                                                             \
        const unsigned short* gsrc_ = (isB) ? g_WT : g_XHL;                       \
        _Pragma("unroll")                                                         \
        for (int h2 = 0; h2 < 2; ++h2) {                                          \
            int ck = h2 * 512 + tid;                                              \
            int row = ck >> 3, unit = ck & 7;                                     \
            int su = unit ^ (row & 7);                                            \
            gload16(&gsrc_[(size_t)((rowbase) + (half) * 128 + row) * KP          \
                           + (colbase) + su * 8],                                 \
                    &lds[(cbuf) * 32768 + (isB) * 16384 + (half) * 8192 + ck * 8]);\
        }                                                                         \
    }

    // Prologue: tile0 fully + tile1 B; wait all but last 2 stages (4 loads).
    STAGE(0, 0, 0, colsA_of(0), bm); STAGE(0, 0, 1, colsA_of(0), bm);
    STAGE(0, 1, 0, colsB_of(0), bn); STAGE(0, 1, 1, colsB_of(0), bn);
    STAGE(1, 1, 0, colsB_of(1), bn); STAGE(1, 1, 1, colsB_of(1), bn);
    asm volatile("s_waitcnt vmcnt(4)" ::: "memory");
    __builtin_amdgcn_s_barrier();

    for (int kt = 0; kt < NT; ++kt) {
        const int cur = kt & 1;
        const int nxt = cur ^ 1;
        unsigned short* Abuf = &lds[cur * 32768];
        unsigned short* Bbuf = &lds[cur * 32768 + 16384];
        const int cA1 = colsA_of(kt + 1);
        const int cB2 = colsB_of(kt + 2);

        bf16x8 bf[4][2];
        #pragma unroll
        for (int q = 0; q < 4; ++q) {
            if (q == 0) {
                #pragma unroll
                for (int ni = 0; ni < 4; ++ni)
                    #pragma unroll
                    for (int kk = 0; kk < 2; ++kk) {
                        int row = wc * 64 + ni * 16 + r16;
                        int u = kk * 4 + sgrp;
                        bf[ni][kk] = *(const bf16x8*)&Bbuf[row * 64 + (u ^ (row & 7)) * 8];
                    }
            }
            bf16x8 af[2][2];
            #pragma unroll
            for (int dm = 0; dm < 2; ++dm)
                #pragma unroll
                for (int kk = 0; kk < 2; ++kk) {
                    int row = wr * 128 + (q * 2 + dm) * 16 + r16;
                    int u = kk * 4 + sgrp;
                    af[dm][kk] = *(const bf16x8*)&Abuf[row * 64 + (u ^ (row & 7)) * 8];
                }
            // Prefetch schedule: t+1.A0, t+1.A1, t+2.B0, t+2.B1.
            if (q == 0)      { STAGE(nxt, 0, 0, cA1, bm); }
            else if (q == 1) { STAGE(nxt, 0, 1, cA1, bm); }
            else if (q == 2) { STAGE(cur, 1, 0, cB2, bn); }
            else             { STAGE(cur, 1, 1, cB2, bn); }
            __builtin_amdgcn_s_barrier();
            __builtin_amdgcn_s_setprio(1);
            #pragma unroll
            for (int dm = 0; dm < 2; ++dm)
                #pragma unroll
                for (int ni = 0; ni < 4; ++ni)
                    #pragma unroll
                    for (int kk = 0; kk < 2; ++kk)
                        acc[q * 2 + dm][ni] = __builtin_amdgcn_mfma_f32_16x16x32_bf16(
                            af[dm][kk], bf[ni][kk], acc[q * 2 + dm][ni], 0, 0, 0);
            __builtin_amdgcn_s_setprio(0);
            __builtin_amdgcn_s_barrier();
        }
        // Checkpoint: allow q2,q3's stages (4 loads) in flight; t+1 fully landed.
        asm volatile("s_waitcnt vmcnt(4)" ::: "memory");
    }
    asm volatile("s_waitcnt vmcnt(0)" ::: "memory");
    #undef STAGE

    // Epilogue: z = (c + bias)*1.7015 -> sigmoid -> mean over 8 cols -> level
    #pragma unroll
    for (int mi = 0; mi < 8; ++mi) {
        #pragma unroll
        for (int ni = 0; ni < 4; ++ni) {
            int n = bn + wc * 64 + ni * 16 + r16;
            float bb = bias[n];
            #pragma unroll
            for (int r = 0; r < 4; ++r) {
                float z = (acc[mi][ni][r] + bb) * 1.7015f;
                float s = 1.0f / (1.0f + expf(-z));
                s += __shfl_xor(s, 1);
                s += __shfl_xor(s, 2);
                s += __shfl_xor(s, 4);
                if ((lane & 7) == 0) {
                    float gcont = s * 0.125f;
                    int lvl = (int)rintf(gcont * 7.0f);
                    lvl = min(7, max(0, lvl));
                    int m = bm + wr * 128 + mi * 16 + sgrp * 4 + r;
                    g_levels[(size_t)m * NN + (n >> 3)] = (unsigned char)lvl;
                }
            }
        }
    }
}

// ---------------------------------------------------------------------------
// apply: gather U by level, rotate, blend, write bf16 pairs [imag, real].
// ---------------------------------------------------------------------------
__global__ __launch_bounds__(256)
void apply_kernel(const float* __restrict__ xr,
                  const float* __restrict__ xi,
                  unsigned short* __restrict__ out)
{
    int t = blockIdx.x * 256 + threadIdx.x;
    int bs = t >> 7;
    int n = t & 127;

    int L = g_levels[t];
    const float* Up = g_U + ((size_t)(L * NN + n)) * 128;
    const float* xrp = xr + (size_t)bs * DD + n * 8;
    const float* xip = xi + (size_t)bs * DD + n * 8;

    float4 r0 = *(const float4*)xrp;
    float4 r1 = *(const float4*)(xrp + 4);
    float4 i0 = *(const float4*)xip;
    float4 i1 = *(const float4*)(xip + 4);
    float xrv[8] = {r0.x, r0.y, r0.z, r0.w, r1.x, r1.y, r1.z, r1.w};
    float xiv[8] = {i0.x, i0.y, i0.z, i0.w, i1.x, i1.y, i1.z, i1.w};

    float gq = (float)L * (1.0f / 7.0f);
    float scale = gq / (gq + 1e-7f);

    unsigned int pk[8];
    #pragma unroll
    for (int oo = 0; oo < 8; ++oo) {
        float4 ur0 = *(const float4*)&Up[oo * 8];
        float4 ur1 = *(const float4*)&Up[oo * 8 + 4];
        float4 ui0 = *(const float4*)&Up[64 + oo * 8];
        float4 ui1 = *(const float4*)&Up[64 + oo * 8 + 4];
        float ur[8] = {ur0.x, ur0.y, ur0.z, ur0.w, ur1.x, ur1.y, ur1.z, ur1.w};
        float ui[8] = {ui0.x, ui0.y, ui0.z, ui0.w, ui1.x, ui1.y, ui1.z, ui1.w};
        float uxr = 0.0f, uxi = 0.0f;
        #pragma unroll
        for (int q = 0; q < 8; ++q) {
            uxr += ur[q] * xrv[q] - ui[q] * xiv[q];
            uxi += ur[q] * xiv[q] + ui[q] * xrv[q];
        }
        float outr = xrv[oo] + scale * (uxr - xrv[oo]);
        float outi = xiv[oo] + scale * (uxi - xiv[oo]);
        pk[oo] = bf16_bits(outi) | (bf16_bits(outr) << 16);   // [imag, real]
    }

    unsigned int* ob = (unsigned int*)(out + 2 * ((size_t)bs * DD + (size_t)n * 8));
    *(uint4*)&ob[0] = make_uint4(pk[0], pk[1], pk[2], pk[3]);
    *(uint4*)&ob[4] = make_uint4(pk[4], pk[5], pk[6], pk[7]);
}

// ---------------------------------------------------------------------------
extern "C" void kernel_launch(void* const* d_in, const int* in_sizes, int n_in,
                              void* d_out, int out_size, void* d_ws, size_t ws_size,
                              hipStream_t stream) {
    (void)in_sizes; (void)n_in; (void)out_size; (void)d_ws; (void)ws_size;
    const float* x_real = (const float*)d_in[0];
    const float* x_imag = (const float*)d_in[1];
    const float* A_real = (const float*)d_in[2];
    const float* A_imag = (const float*)d_in[3];
    const float* W_gate = (const float*)d_in[4];
    const float* b_gate = (const float*)d_in[5];
    unsigned short* out = (unsigned short*)d_out;

    hipLaunchKernelGGL(prep_kernel, dim3(2 * MM + WT_BLOCKS + KLV * NN), dim3(256),
                       0, stream, x_real, x_imag, W_gate, A_real, A_imag);
    hipLaunchKernelGGL(gate_mfma8, dim3(256), dim3(512), 0, stream, b_gate);
    hipLaunchKernelGGL(apply_kernel, dim3((MM * NN) / 256), dim3(256), 0, stream,
                       x_real, x_imag, out);
}

// Round 12
// 391.818 us; speedup vs baseline: 2.5065x; 1.0035x over previous
//
#include <hip/hip_runtime.h>
#include <hip/hip_bf16.h>
#include <math.h>

// Problem constants
#define BB 4
#define SS 4096
#define DD 1024
#define NN 128           // D / 8
#define KLV 8            // quantization levels
#define MM (BB*SS)       // 16384 rows
#define KC 2048          // x_cat width
#define KP 4096          // [hi | lo] padded width
#define NT 96            // virtual K tiles: 3 terms x 32 chunks of 64

typedef short bf16x8 __attribute__((ext_vector_type(8)));
typedef float f32x4 __attribute__((ext_vector_type(4)));

// Static device scratch.
__device__ float g_U[KLV * NN * 128];              // 512 KB  Cayley table
__device__ unsigned char g_levels[MM * NN];        // 2 MB    per-(token,block) level
__device__ unsigned short g_XHL[(size_t)MM * KP];  // 134 MB  [m][0..2047]=hi(x_cat), [2048..]=lo
__device__ unsigned short g_WT[(size_t)DD * KP];   // 8 MB    [n][0..2047]=wh, [2048..]=wl (W^T)

// f32 -> bf16 bits, round-to-nearest-even
__device__ __forceinline__ unsigned int bf16_bits(float f) {
    union { float f; unsigned int u; } v;
    v.f = f;
    unsigned int lsb = (v.u >> 16) & 1u;
    return (v.u + 0x7FFFu + lsb) >> 16;
}
__device__ __forceinline__ float bfbits2f(unsigned int b) {
    union { unsigned int u; float f; } v;
    v.u = b << 16;
    return v.f;
}

// async global->LDS 16B copy
__device__ __forceinline__ void gload16(const void* g, void* l) {
    __builtin_amdgcn_global_load_lds(
        (const __attribute__((address_space(1))) unsigned int*)g,
        (__attribute__((address_space(3))) unsigned int*)l, 16, 0, 0);
}

// ---------------------------------------------------------------------------
// prep_kernel: fused {convert_x | convert_wt | cayley} by blockIdx range.
// ---------------------------------------------------------------------------
#define WT_BLOCKS (64 * 32)
__global__ __launch_bounds__(256)
void prep_kernel(const float* __restrict__ xr, const float* __restrict__ xi,
                 const float* __restrict__ W,
                 const float* __restrict__ A_real,
                 const float* __restrict__ A_imag)
{
    __shared__ __align__(16) float sh[33 * 32];   // wt: tile[32][33]; cayley: M[16][34]
    int blk = blockIdx.x;
    int t = threadIdx.x;

    if (blk < 2 * MM) {
        // ---- convert_x: x f32 -> bf16 hi|lo planes ----
        int plane = blk & 1;
        int m = blk >> 1;
        const float* src = plane ? xi : xr;
        float4 v = *(const float4*)&src[(size_t)m * DD + t * 4];
        float f[4] = {v.x, v.y, v.z, v.w};
        unsigned int hi[4], lo[4];
        #pragma unroll
        for (int q = 0; q < 4; ++q) {
            hi[q] = bf16_bits(f[q]);
            lo[q] = bf16_bits(f[q] - bfbits2f(hi[q]));
        }
        size_t base = (size_t)m * KP + plane * DD + t * 4;
        *(uint2*)&g_XHL[base]        = make_uint2(hi[0] | (hi[1] << 16), hi[2] | (hi[3] << 16));
        *(uint2*)&g_XHL[base + 2048] = make_uint2(lo[0] | (lo[1] << 16), lo[2] | (lo[3] << 16));
        return;
    }
    blk -= 2 * MM;

    if (blk < WT_BLOCKS) {
        // ---- convert_wt: W[k][n] -> g_WT[n][k] bf16 hi|lo (32x32 transpose) ----
        float (*tile)[33] = (float(*)[33])sh;
        int bk = (blk >> 5) * 32;
        int bn = (blk & 31) * 32;

        int kk = t >> 3;
        int nn4 = (t & 7) * 4;
        float4 v = *(const float4*)&W[(size_t)(bk + kk) * DD + bn + nn4];
        tile[kk][nn4 + 0] = v.x; tile[kk][nn4 + 1] = v.y;
        tile[kk][nn4 + 2] = v.z; tile[kk][nn4 + 3] = v.w;
        __syncthreads();

        int n2 = t >> 3;
        int k4 = (t & 7) * 4;
        unsigned int hi[4], lo[4];
        #pragma unroll
        for (int q = 0; q < 4; ++q) {
            float f = tile[k4 + q][n2];
            hi[q] = bf16_bits(f);
            lo[q] = bf16_bits(f - bfbits2f(hi[q]));
        }
        size_t base = (size_t)(bn + n2) * KP + bk + k4;
        *(uint2*)&g_WT[base]        = make_uint2(hi[0] | (hi[1] << 16), hi[2] | (hi[3] << 16));
        *(uint2*)&g_WT[base + 2048] = make_uint2(lo[0] | (lo[1] << 16), lo[2] | (lo[3] << 16));
        return;
    }
    blk -= WT_BLOCKS;

    {
        // ---- cayley: Gauss-Jordan on 16x16 augmented system ----
        float (*M)[34] = (float(*)[34])sh;
        int L = blk >> 7;
        int n = blk & 127;
        float g = (float)L * (1.0f / 7.0f);

        int i = t >> 4;
        int j = t & 15;

        const float* Ar = A_real + n * 64;
        const float* Ai = A_imag + n * 64;
        int bi = i >> 3;
        int ii = i & 7, jj = j & 7;

        float ar = (Ar[ii * 8 + jj] - Ar[jj * 8 + ii]) * 0.5f * g;
        float ai = (Ai[ii * 8 + jj] + Ai[jj * 8 + ii]) * 0.5f * g;
        float eye = (ii == jj) ? 1.0f : 0.0f;

        int bj = j >> 3;
        float lhs, rhs;
        if (bi == bj) { lhs = eye + ar; rhs = eye - ar; }
        else if (bi == 0) { lhs = -ai; rhs = ai; }
        else { lhs = ai; rhs = -ai; }

        M[i][j] = lhs;
        M[i][16 + j] = rhs;
        __syncthreads();

        for (int k = 0; k < 16; ++k) {
            float f = M[i][k] / M[k][k];
            __syncthreads();
            if (i != k) {
                M[i][j]      -= f * M[k][j];
                M[i][16 + j] -= f * M[k][16 + j];
            }
            __syncthreads();
        }

        float x = M[i][16 + j] / M[i][i];
        if (j < 8) {
            g_U[(size_t)blk * 128 + bi * 64 + ii * 8 + j] = x;
        }
    }
}

// ---------------------------------------------------------------------------
// gate_mfma8: 256x256 tile, BK=64, 8 waves, counted-vmcnt pipeline.
// Barrier-minimized: exactly 2 barriers per K-tile.
//   - q1-end barrier: protects cur-B (read at q0) from q2/q3's t+2-B prefetch.
//   - q3-end: vmcnt(4) THEN barrier: all waves' t+1-A stages drained before
//     any wave reads the nxt buffer (also fixes round-11's vmcnt-after-barrier
//     ordering). q2/q3's 4 B-loads stay in flight across the tile boundary.
// Virtual K = 96 tiles: chunk=kt/3, term=kt%3 (xh*wh, xl*wh, xh*wl).
// ---------------------------------------------------------------------------
__device__ __forceinline__ int colsA_of(int kt) {
    int k = (kt < NT) ? kt : 0;
    int ch = k / 3, tm = k - 3 * ch;
    return ch * 64 + (tm == 1 ? 2048 : 0);
}
__device__ __forceinline__ int colsB_of(int kt) {
    int k = (kt < NT) ? kt : 0;
    int ch = k / 3, tm = k - 3 * ch;
    return ch * 64 + (tm == 2 ? 2048 : 0);
}

__global__ __launch_bounds__(512, 1)
void gate_mfma8(const float* __restrict__ bias)
{
    __shared__ __align__(16) unsigned short lds[65536];   // 128 KB: 2 bufs x (A 16K + B 16K shorts)

    const int tid = threadIdx.x;
    const int bid = blockIdx.x;          // 0..255
    // bid%8 round-robins across XCDs [m09]; keep an m-strip's 4 n-tiles on
    // one XCD so the A-strip is fetched once into that XCD's L2.
    const int xcd = bid & 7;
    const int grp = bid >> 3;            // 0..31
    const int mt = xcd * 8 + (grp >> 2); // 0..63
    const int nt = grp & 3;              // 0..3
    const int bm = mt * 256, bn = nt * 256;

    const int lane = tid & 63;
    const int wv = tid >> 6;             // 8 waves: 2M x 4N
    const int wr = wv >> 2;              // 0..1
    const int wc = wv & 3;               // 0..3
    const int r16 = lane & 15, sgrp = lane >> 4;

    f32x4 acc[8][4];
    #pragma unroll
    for (int a = 0; a < 8; ++a)
        #pragma unroll
        for (int b = 0; b < 4; ++b) {
            f32x4 z = {0.0f, 0.0f, 0.0f, 0.0f};
            acc[a][b] = z;
        }

    // STAGE one half-tile (128 rows x 64 cols bf16 = 16KB): 2 gloads/thread.
    // Linear LDS dest; source col-unit pre-swizzled by ^(row&7)  [rule 21].
    #define STAGE(cbuf, isB, half, colbase, rowbase)                              \
    {                                                                             \
        const unsigned short* gsrc_ = (isB) ? g_WT : g_XHL;                       \
        _Pragma("unroll")                                                         \
        for (int h2 = 0; h2 < 2; ++h2) {                                          \
            int ck = h2 * 512 + tid;                                              \
            int row = ck >> 3, unit = ck & 7;                                     \
            int su = unit ^ (row & 7);                                            \
            gload16(&gsrc_[(size_t)((rowbase) + (half) * 128 + row) * KP          \
                           + (colbase) + su * 8],                                 \
                    &lds[(cbuf) * 32768 + (isB) * 16384 + (half) * 8192 + ck * 8]);\
        }                                                                         \
    }

    // Prologue: tile0 fully + tile1 B; drain tile0 (8 loads), leave tile1-B (4).
    STAGE(0, 0, 0, colsA_of(0), bm); STAGE(0, 0, 1, colsA_of(0), bm);
    STAGE(0, 1, 0, colsB_of(0), bn); STAGE(0, 1, 1, colsB_of(0), bn);
    STAGE(1, 1, 0, colsB_of(1), bn); STAGE(1, 1, 1, colsB_of(1), bn);
    asm volatile("s_waitcnt vmcnt(4)" ::: "memory");
    __builtin_amdgcn_s_barrier();

    for (int kt = 0; kt < NT; ++kt) {
        const int cur = kt & 1;
        const int nxt = cur ^ 1;
        unsigned short* Abuf = &lds[cur * 32768];
        unsigned short* Bbuf = &lds[cur * 32768 + 16384];
        const int cA1 = colsA_of(kt + 1);
        const int cB2 = colsB_of(kt + 2);

        bf16x8 bf[4][2];
        #pragma unroll
        for (int q = 0; q < 4; ++q) {
            if (q == 0) {
                #pragma unroll
                for (int ni = 0; ni < 4; ++ni)
                    #pragma unroll
                    for (int kk = 0; kk < 2; ++kk) {
                        int row = wc * 64 + ni * 16 + r16;
                        int u = kk * 4 + sgrp;
                        bf[ni][kk] = *(const bf16x8*)&Bbuf[row * 64 + (u ^ (row & 7)) * 8];
                    }
            }
            bf16x8 af[2][2];
            #pragma unroll
            for (int dm = 0; dm < 2; ++dm)
                #pragma unroll
                for (int kk = 0; kk < 2; ++kk) {
                    int row = wr * 128 + (q * 2 + dm) * 16 + r16;
                    int u = kk * 4 + sgrp;
                    af[dm][kk] = *(const bf16x8*)&Abuf[row * 64 + (u ^ (row & 7)) * 8];
                }
            // Prefetch: t+1.A0, t+1.A1, t+2.B0, t+2.B1.
            if (q == 0)      { STAGE(nxt, 0, 0, cA1, bm); }
            else if (q == 1) { STAGE(nxt, 0, 1, cA1, bm); }
            else if (q == 2) { STAGE(cur, 1, 0, cB2, bn); }
            else             { STAGE(cur, 1, 1, cB2, bn); }
            __builtin_amdgcn_s_setprio(1);
            #pragma unroll
            for (int dm = 0; dm < 2; ++dm)
                #pragma unroll
                for (int ni = 0; ni < 4; ++ni)
                    #pragma unroll
                    for (int kk = 0; kk < 2; ++kk)
                        acc[q * 2 + dm][ni] = __builtin_amdgcn_mfma_f32_16x16x32_bf16(
                            af[dm][kk], bf[ni][kk], acc[q * 2 + dm][ni], 0, 0, 0);
            __builtin_amdgcn_s_setprio(0);
            if (q == 1) {
                // C1: cur-B consumed by all waves (their q0 MFMA) before q2's
                // t+2-B prefetch may overwrite it.
                __builtin_amdgcn_s_barrier();
            }
            if (q == 3) {
                // C3: drain own t+1-A (and older) loads, THEN collectively
                // barrier so every wave's stages have landed before any wave
                // reads the nxt buffer. Leaves q2/q3's 4 B-loads in flight.
                asm volatile("s_waitcnt vmcnt(4)" ::: "memory");
                __builtin_amdgcn_s_barrier();
            }
        }
    }
    asm volatile("s_waitcnt vmcnt(0)" ::: "memory");
    #undef STAGE

    // Epilogue: z = (c + bias)*1.7015 -> sigmoid -> mean over 8 cols -> level
    #pragma unroll
    for (int mi = 0; mi < 8; ++mi) {
        #pragma unroll
        for (int ni = 0; ni < 4; ++ni) {
            int n = bn + wc * 64 + ni * 16 + r16;
            float bb = bias[n];
            #pragma unroll
            for (int r = 0; r < 4; ++r) {
                float z = (acc[mi][ni][r] + bb) * 1.7015f;
                float s = 1.0f / (1.0f + expf(-z));
                s += __shfl_xor(s, 1);
                s += __shfl_xor(s, 2);
                s += __shfl_xor(s, 4);
                if ((lane & 7) == 0) {
                    float gcont = s * 0.125f;
                    int lvl = (int)rintf(gcont * 7.0f);
                    lvl = min(7, max(0, lvl));
                    int m = bm + wr * 128 + mi * 16 + sgrp * 4 + r;
                    g_levels[(size_t)m * NN + (n >> 3)] = (unsigned char)lvl;
                }
            }
        }
    }
}

// ---------------------------------------------------------------------------
// apply: gather U by level, rotate, blend, write bf16 pairs [imag, real].
// ---------------------------------------------------------------------------
__global__ __launch_bounds__(256)
void apply_kernel(const float* __restrict__ xr,
                  const float* __restrict__ xi,
                  unsigned short* __restrict__ out)
{
    int t = blockIdx.x * 256 + threadIdx.x;
    int bs = t >> 7;
    int n = t & 127;

    int L = g_levels[t];
    const float* Up = g_U + ((size_t)(L * NN + n)) * 128;
    const float* xrp = xr + (size_t)bs * DD + n * 8;
    const float* xip = xi + (size_t)bs * DD + n * 8;

    float4 r0 = *(const float4*)xrp;
    float4 r1 = *(const float4*)(xrp + 4);
    float4 i0 = *(const float4*)xip;
    float4 i1 = *(const float4*)(xip + 4);
    float xrv[8] = {r0.x, r0.y, r0.z, r0.w, r1.x, r1.y, r1.z, r1.w};
    float xiv[8] = {i0.x, i0.y, i0.z, i0.w, i1.x, i1.y, i1.z, i1.w};

    float gq = (float)L * (1.0f / 7.0f);
    float scale = gq / (gq + 1e-7f);

    unsigned int pk[8];
    #pragma unroll
    for (int oo = 0; oo < 8; ++oo) {
        float4 ur0 = *(const float4*)&Up[oo * 8];
        float4 ur1 = *(const float4*)&Up[oo * 8 + 4];
        float4 ui0 = *(const float4*)&Up[64 + oo * 8];
        float4 ui1 = *(const float4*)&Up[64 + oo * 8 + 4];
        float ur[8] = {ur0.x, ur0.y, ur0.z, ur0.w, ur1.x, ur1.y, ur1.z, ur1.w};
        float ui[8] = {ui0.x, ui0.y, ui0.z, ui0.w, ui1.x, ui1.y, ui1.z, ui1.w};
        float uxr = 0.0f, uxi = 0.0f;
        #pragma unroll
        for (int q = 0; q < 8; ++q) {
            uxr += ur[q] * xrv[q] - ui[q] * xiv[q];
            uxi += ur[q] * xiv[q] + ui[q] * xrv[q];
        }
        float outr = xrv[oo] + scale * (uxr - xrv[oo]);
        float outi = xiv[oo] + scale * (uxi - xiv[oo]);
        pk[oo] = bf16_bits(outi) | (bf16_bits(outr) << 16);   // [imag, real]
    }

    unsigned int* ob = (unsigned int*)(out + 2 * ((size_t)bs * DD + (size_t)n * 8));
    *(uint4*)&ob[0] = make_uint4(pk[0], pk[1], pk[2], pk[3]);
    *(uint4*)&ob[4] = make_uint4(pk[4], pk[5], pk[6], pk[7]);
}

// ---------------------------------------------------------------------------
extern "C" void kernel_launch(void* const* d_in, const int* in_sizes, int n_in,
                              void* d_out, int out_size, void* d_ws, size_t ws_size,
                              hipStream_t stream) {
    (void)in_sizes; (void)n_in; (void)out_size; (void)d_ws; (void)ws_size;
    const float* x_real = (const float*)d_in[0];
    const float* x_imag = (const float*)d_in[1];
    const float* A_real = (const float*)d_in[2];
    const float* A_imag = (const float*)d_in[3];
    const float* W_gate = (const float*)d_in[4];
    const float* b_gate = (const float*)d_in[5];
    unsigned short* out = (unsigned short*)d_out;

    hipLaunchKernelGGL(prep_kernel, dim3(2 * MM + WT_BLOCKS + KLV * NN), dim3(256),
                       0, stream, x_real, x_imag, W_gate, A_real, A_imag);
    hipLaunchKernelGGL(gate_mfma8, dim3(256), dim3(512), 0, stream, b_gate);
    hipLaunchKernelGGL(apply_kernel, dim3((MM * NN) / 256), dim3(256), 0, stream,
                       x_real, x_imag, out);
}

// Round 13
// 390.019 us; speedup vs baseline: 2.5181x; 1.0046x over previous
//
#include <hip/hip_runtime.h>
#include <hip/hip_bf16.h>
#include <math.h>

// Problem constants
#define BB 4
#define SS 4096
#define DD 1024
#define NN 128           // D / 8
#define KLV 8            // quantization levels
#define MM (BB*SS)       // 16384 rows
#define KC 2048          // x_cat width
#define KP 4096          // [hi | lo] padded width
#define NT 96            // virtual K tiles: 3 terms x 32 chunks of 64

typedef short bf16x8 __attribute__((ext_vector_type(8)));
typedef float f32x4 __attribute__((ext_vector_type(4)));

// Static device scratch.
__device__ float g_U[KLV * NN * 128];              // 512 KB  Cayley table
__device__ unsigned char g_levels[MM * NN];        // 2 MB    per-(token,block) level
__device__ unsigned short g_XHL[(size_t)MM * KP];  // 134 MB  [m][0..2047]=hi(x_cat), [2048..]=lo
__device__ unsigned short g_WT[(size_t)DD * KP];   // 8 MB    [n][0..2047]=wh, [2048..]=wl (W^T)

// f32 -> bf16 bits, round-to-nearest-even
__device__ __forceinline__ unsigned int bf16_bits(float f) {
    union { float f; unsigned int u; } v;
    v.f = f;
    unsigned int lsb = (v.u >> 16) & 1u;
    return (v.u + 0x7FFFu + lsb) >> 16;
}
__device__ __forceinline__ float bfbits2f(unsigned int b) {
    union { unsigned int u; float f; } v;
    v.u = b << 16;
    return v.f;
}

// async global->LDS 16B copy
__device__ __forceinline__ void gload16(const void* g, void* l) {
    __builtin_amdgcn_global_load_lds(
        (const __attribute__((address_space(1))) unsigned int*)g,
        (__attribute__((address_space(3))) unsigned int*)l, 16, 0, 0);
}

// ---------------------------------------------------------------------------
// prep_kernel: fused {convert_x | convert_wt | cayley} by blockIdx range.
// ---------------------------------------------------------------------------
#define WT_BLOCKS (64 * 32)
__global__ __launch_bounds__(256)
void prep_kernel(const float* __restrict__ xr, const float* __restrict__ xi,
                 const float* __restrict__ W,
                 const float* __restrict__ A_real,
                 const float* __restrict__ A_imag)
{
    __shared__ __align__(16) float sh[33 * 32];   // wt: tile[32][33]; cayley: M[16][34]
    int blk = blockIdx.x;
    int t = threadIdx.x;

    if (blk < 2 * MM) {
        // ---- convert_x: x f32 -> bf16 hi|lo planes ----
        int plane = blk & 1;
        int m = blk >> 1;
        const float* src = plane ? xi : xr;
        float4 v = *(const float4*)&src[(size_t)m * DD + t * 4];
        float f[4] = {v.x, v.y, v.z, v.w};
        unsigned int hi[4], lo[4];
        #pragma unroll
        for (int q = 0; q < 4; ++q) {
            hi[q] = bf16_bits(f[q]);
            lo[q] = bf16_bits(f[q] - bfbits2f(hi[q]));
        }
        size_t base = (size_t)m * KP + plane * DD + t * 4;
        *(uint2*)&g_XHL[base]        = make_uint2(hi[0] | (hi[1] << 16), hi[2] | (hi[3] << 16));
        *(uint2*)&g_XHL[base + 2048] = make_uint2(lo[0] | (lo[1] << 16), lo[2] | (lo[3] << 16));
        return;
    }
    blk -= 2 * MM;

    if (blk < WT_BLOCKS) {
        // ---- convert_wt: W[k][n] -> g_WT[n][k] bf16 hi|lo (32x32 transpose) ----
        float (*tile)[33] = (float(*)[33])sh;
        int bk = (blk >> 5) * 32;
        int bn = (blk & 31) * 32;

        int kk = t >> 3;
        int nn4 = (t & 7) * 4;
        float4 v = *(const float4*)&W[(size_t)(bk + kk) * DD + bn + nn4];
        tile[kk][nn4 + 0] = v.x; tile[kk][nn4 + 1] = v.y;
        tile[kk][nn4 + 2] = v.z; tile[kk][nn4 + 3] = v.w;
        __syncthreads();

        int n2 = t >> 3;
        int k4 = (t & 7) * 4;
        unsigned int hi[4], lo[4];
        #pragma unroll
        for (int q = 0; q < 4; ++q) {
            float f = tile[k4 + q][n2];
            hi[q] = bf16_bits(f);
            lo[q] = bf16_bits(f - bfbits2f(hi[q]));
        }
        size_t base = (size_t)(bn + n2) * KP + bk + k4;
        *(uint2*)&g_WT[base]        = make_uint2(hi[0] | (hi[1] << 16), hi[2] | (hi[3] << 16));
        *(uint2*)&g_WT[base + 2048] = make_uint2(lo[0] | (lo[1] << 16), lo[2] | (lo[3] << 16));
        return;
    }
    blk -= WT_BLOCKS;

    {
        // ---- cayley: Gauss-Jordan on 16x16 augmented system ----
        float (*M)[34] = (float(*)[34])sh;
        int L = blk >> 7;
        int n = blk & 127;
        float g = (float)L * (1.0f / 7.0f);

        int i = t >> 4;
        int j = t & 15;

        const float* Ar = A_real + n * 64;
        const float* Ai = A_imag + n * 64;
        int bi = i >> 3;
        int ii = i & 7, jj = j & 7;

        float ar = (Ar[ii * 8 + jj] - Ar[jj * 8 + ii]) * 0.5f * g;
        float ai = (Ai[ii * 8 + jj] + Ai[jj * 8 + ii]) * 0.5f * g;
        float eye = (ii == jj) ? 1.0f : 0.0f;

        int bj = j >> 3;
        float lhs, rhs;
        if (bi == bj) { lhs = eye + ar; rhs = eye - ar; }
        else if (bi == 0) { lhs = -ai; rhs = ai; }
        else { lhs = ai; rhs = -ai; }

        M[i][j] = lhs;
        M[i][16 + j] = rhs;
        __syncthreads();

        for (int k = 0; k < 16; ++k) {
            float f = M[i][k] / M[k][k];
            __syncthreads();
            if (i != k) {
                M[i][j]      -= f * M[k][j];
                M[i][16 + j] -= f * M[k][16 + j];
            }
            __syncthreads();
        }

        float x = M[i][16 + j] / M[i][i];
        if (j < 8) {
            g_U[(size_t)blk * 128 + bi * 64 + ii * 8 + j] = x;
        }
    }
}

// ---------------------------------------------------------------------------
// gate_mfma8: 256x256 tile, BK=64, 8 waves, counted-vmcnt pipeline,
// 2 barriers/tile, and WITHIN-WAVE register pipelining of fragment reads:
// phase q+1's A-frag ds_reads are issued before phase q's MFMA burst so the
// LDS pipe overlaps the matrix pipe (round-12 counters showed them serial).
// Virtual K = 96 tiles: chunk=kt/3, term=kt%3 (xh*wh, xl*wh, xh*wl).
// ---------------------------------------------------------------------------
__device__ __forceinline__ int colsA_of(int kt) {
    int k = (kt < NT) ? kt : 0;
    int ch = k / 3, tm = k - 3 * ch;
    return ch * 64 + (tm == 1 ? 2048 : 0);
}
__device__ __forceinline__ int colsB_of(int kt) {
    int k = (kt < NT) ? kt : 0;
    int ch = k / 3, tm = k - 3 * ch;
    return ch * 64 + (tm == 2 ? 2048 : 0);
}

__global__ __launch_bounds__(512, 1)
void gate_mfma8(const float* __restrict__ bias)
{
    __shared__ __align__(16) unsigned short lds[65536];   // 128 KB: 2 bufs x (A 16K + B 16K shorts)

    const int tid = threadIdx.x;
    const int bid = blockIdx.x;          // 0..255
    // bid%8 round-robins across XCDs [m09]; keep an m-strip's 4 n-tiles on
    // one XCD so the A-strip is fetched once into that XCD's L2.
    const int xcd = bid & 7;
    const int grp = bid >> 3;            // 0..31
    const int mt = xcd * 8 + (grp >> 2); // 0..63
    const int nt = grp & 3;              // 0..3
    const int bm = mt * 256, bn = nt * 256;

    const int lane = tid & 63;
    const int wv = tid >> 6;             // 8 waves: 2M x 4N
    const int wr = wv >> 2;              // 0..1
    const int wc = wv & 3;               // 0..3
    const int r16 = lane & 15, sgrp = lane >> 4;

    f32x4 acc[8][4];
    #pragma unroll
    for (int a = 0; a < 8; ++a)
        #pragma unroll
        for (int b = 0; b < 4; ++b) {
            f32x4 z = {0.0f, 0.0f, 0.0f, 0.0f};
            acc[a][b] = z;
        }

    // STAGE one half-tile (128 rows x 64 cols bf16 = 16KB): 2 gloads/thread.
    // Linear LDS dest; source col-unit pre-swizzled by ^(row&7)  [rule 21].
    #define STAGE(cbuf, isB, half, colbase, rowbase)                              \
    {                                                                             \
        const unsigned short* gsrc_ = (isB) ? g_WT : g_XHL;                       \
        _Pragma("unroll")                                                         \
        for (int h2 = 0; h2 < 2; ++h2) {                                          \
            int ck = h2 * 512 + tid;                                              \
            int row = ck >> 3, unit = ck & 7;                                     \
            int su = unit ^ (row & 7);                                            \
            gload16(&gsrc_[(size_t)((rowbase) + (half) * 128 + row) * KP          \
                           + (colbase) + su * 8],                                 \
                    &lds[(cbuf) * 32768 + (isB) * 16384 + (half) * 8192 + ck * 8]);\
        }                                                                         \
    }

    // Read phase-q A-frags into a named register buffer (static indexing).
    #define LOADA(dst, q)                                                         \
    {                                                                             \
        _Pragma("unroll")                                                         \
        for (int dm = 0; dm < 2; ++dm)                                            \
            _Pragma("unroll")                                                     \
            for (int kk = 0; kk < 2; ++kk) {                                      \
                int row = wr * 128 + ((q) * 2 + dm) * 16 + r16;                   \
                int u = kk * 4 + sgrp;                                            \
                (dst)[dm][kk] = *(const bf16x8*)&Abuf[row * 64 + (u ^ (row & 7)) * 8]; \
            }                                                                     \
    }

    #define MFMAQ(q, af)                                                          \
    {                                                                             \
        __builtin_amdgcn_s_setprio(1);                                            \
        _Pragma("unroll")                                                         \
        for (int dm = 0; dm < 2; ++dm)                                            \
            _Pragma("unroll")                                                     \
            for (int ni = 0; ni < 4; ++ni)                                        \
                _Pragma("unroll")                                                 \
                for (int kk = 0; kk < 2; ++kk)                                    \
                    acc[(q) * 2 + dm][ni] = __builtin_amdgcn_mfma_f32_16x16x32_bf16( \
                        (af)[dm][kk], bf[ni][kk], acc[(q) * 2 + dm][ni], 0, 0, 0);\
        __builtin_amdgcn_s_setprio(0);                                            \
    }

    // Prologue: tile0 fully + tile1 B; drain tile0 (8 loads), leave tile1-B (4).
    STAGE(0, 0, 0, colsA_of(0), bm); STAGE(0, 0, 1, colsA_of(0), bm);
    STAGE(0, 1, 0, colsB_of(0), bn); STAGE(0, 1, 1, colsB_of(0), bn);
    STAGE(1, 1, 0, colsB_of(1), bn); STAGE(1, 1, 1, colsB_of(1), bn);
    asm volatile("s_waitcnt vmcnt(4)" ::: "memory");
    __builtin_amdgcn_s_barrier();

    for (int kt = 0; kt < NT; ++kt) {
        const int cur = kt & 1;
        const int nxt = cur ^ 1;
        unsigned short* Abuf = &lds[cur * 32768];
        unsigned short* Bbuf = &lds[cur * 32768 + 16384];
        const int cA1 = colsA_of(kt + 1);
        const int cB2 = colsB_of(kt + 2);

        // Tile top: issue phase-0 A-frags, then all B-frags.
        bf16x8 af0[2][2], af1[2][2], bf[4][2];
        LOADA(af0, 0);
        #pragma unroll
        for (int ni = 0; ni < 4; ++ni)
            #pragma unroll
            for (int kk = 0; kk < 2; ++kk) {
                int row = wc * 64 + ni * 16 + r16;
                int u = kk * 4 + sgrp;
                bf[ni][kk] = *(const bf16x8*)&Bbuf[row * 64 + (u ^ (row & 7)) * 8];
            }

        // ---- phase 0: stage t+1.A0, prefetch A(q1), MFMA q0
        STAGE(nxt, 0, 0, cA1, bm);
        LOADA(af1, 1);
        MFMAQ(0, af0);
        // ---- phase 1: stage t+1.A1, prefetch A(q2), MFMA q1
        STAGE(nxt, 0, 1, cA1, bm);
        LOADA(af0, 2);
        MFMAQ(1, af1);
        // C1: cur-B consumed by all waves before q2's t+2-B stage overwrites.
        __builtin_amdgcn_s_barrier();
        // ---- phase 2: stage t+2.B0, prefetch A(q3), MFMA q2
        STAGE(cur, 1, 0, cB2, bn);
        LOADA(af1, 3);
        MFMAQ(2, af0);
        // ---- phase 3: stage t+2.B1, MFMA q3
        STAGE(cur, 1, 1, cB2, bn);
        MFMAQ(3, af1);
        // C3: drain own t+1-A stages (leave q2/q3's 4 B-loads in flight),
        // then collective barrier before any wave reads the nxt buffer.
        asm volatile("s_waitcnt vmcnt(4)" ::: "memory");
        __builtin_amdgcn_s_barrier();
    }
    asm volatile("s_waitcnt vmcnt(0)" ::: "memory");
    #undef STAGE
    #undef LOADA
    #undef MFMAQ

    // Epilogue: z = (c + bias)*1.7015 -> sigmoid -> mean over 8 cols -> level
    #pragma unroll
    for (int mi = 0; mi < 8; ++mi) {
        #pragma unroll
        for (int ni = 0; ni < 4; ++ni) {
            int n = bn + wc * 64 + ni * 16 + r16;
            float bb = bias[n];
            #pragma unroll
            for (int r = 0; r < 4; ++r) {
                float z = (acc[mi][ni][r] + bb) * 1.7015f;
                float s = 1.0f / (1.0f + expf(-z));
                s += __shfl_xor(s, 1);
                s += __shfl_xor(s, 2);
                s += __shfl_xor(s, 4);
                if ((lane & 7) == 0) {
                    float gcont = s * 0.125f;
                    int lvl = (int)rintf(gcont * 7.0f);
                    lvl = min(7, max(0, lvl));
                    int m = bm + wr * 128 + mi * 16 + sgrp * 4 + r;
                    g_levels[(size_t)m * NN + (n >> 3)] = (unsigned char)lvl;
                }
            }
        }
    }
}

// ---------------------------------------------------------------------------
// apply: gather U by level, rotate, blend, write bf16 pairs [imag, real].
// ---------------------------------------------------------------------------
__global__ __launch_bounds__(256)
void apply_kernel(const float* __restrict__ xr,
                  const float* __restrict__ xi,
                  unsigned short* __restrict__ out)
{
    int t = blockIdx.x * 256 + threadIdx.x;
    int bs = t >> 7;
    int n = t & 127;

    int L = g_levels[t];
    const float* Up = g_U + ((size_t)(L * NN + n)) * 128;
    const float* xrp = xr + (size_t)bs * DD + n * 8;
    const float* xip = xi + (size_t)bs * DD + n * 8;

    float4 r0 = *(const float4*)xrp;
    float4 r1 = *(const float4*)(xrp + 4);
    float4 i0 = *(const float4*)xip;
    float4 i1 = *(const float4*)(xip + 4);
    float xrv[8] = {r0.x, r0.y, r0.z, r0.w, r1.x, r1.y, r1.z, r1.w};
    float xiv[8] = {i0.x, i0.y, i0.z, i0.w, i1.x, i1.y, i1.z, i1.w};

    float gq = (float)L * (1.0f / 7.0f);
    float scale = gq / (gq + 1e-7f);

    unsigned int pk[8];
    #pragma unroll
    for (int oo = 0; oo < 8; ++oo) {
        float4 ur0 = *(const float4*)&Up[oo * 8];
        float4 ur1 = *(const float4*)&Up[oo * 8 + 4];
        float4 ui0 = *(const float4*)&Up[64 + oo * 8];
        float4 ui1 = *(const float4*)&Up[64 + oo * 8 + 4];
        float ur[8] = {ur0.x, ur0.y, ur0.z, ur0.w, ur1.x, ur1.y, ur1.z, ur1.w};
        float ui[8] = {ui0.x, ui0.y, ui0.z, ui0.w, ui1.x, ui1.y, ui1.z, ui1.w};
        float uxr = 0.0f, uxi = 0.0f;
        #pragma unroll
        for (int q = 0; q < 8; ++q) {
            uxr += ur[q] * xrv[q] - ui[q] * xiv[q];
            uxi += ur[q] * xiv[q] + ui[q] * xrv[q];
        }
        float outr = xrv[oo] + scale * (uxr - xrv[oo]);
        float outi = xiv[oo] + scale * (uxi - xiv[oo]);
        pk[oo] = bf16_bits(outi) | (bf16_bits(outr) << 16);   // [imag, real]
    }

    unsigned int* ob = (unsigned int*)(out + 2 * ((size_t)bs * DD + (size_t)n * 8));
    *(uint4*)&ob[0] = make_uint4(pk[0], pk[1], pk[2], pk[3]);
    *(uint4*)&ob[4] = make_uint4(pk[4], pk[5], pk[6], pk[7]);
}

// ---------------------------------------------------------------------------
extern "C" void kernel_launch(void* const* d_in, const int* in_sizes, int n_in,
                              void* d_out, int out_size, void* d_ws, size_t ws_size,
                              hipStream_t stream) {
    (void)in_sizes; (void)n_in; (void)out_size; (void)d_ws; (void)ws_size;
    const float* x_real = (const float*)d_in[0];
    const float* x_imag = (const float*)d_in[1];
    const float* A_real = (const float*)d_in[2];
    const float* A_imag = (const float*)d_in[3];
    const float* W_gate = (const float*)d_in[4];
    const float* b_gate = (const float*)d_in[5];
    unsigned short* out = (unsigned short*)d_out;

    hipLaunchKernelGGL(prep_kernel, dim3(2 * MM + WT_BLOCKS + KLV * NN), dim3(256),
                       0, stream, x_real, x_imag, W_gate, A_real, A_imag);
    hipLaunchKernelGGL(gate_mfma8, dim3(256), dim3(512), 0, stream, b_gate);
    hipLaunchKernelGGL(apply_kernel, dim3((MM * NN) / 256), dim3(256), 0, stream,
                       x_real, x_imag, out);
}

// Round 14
// 386.899 us; speedup vs baseline: 2.5384x; 1.0081x over previous
//
#include <hip/hip_runtime.h>
#include <hip/hip_bf16.h>
#include <math.h>

// Problem constants
#define BB 4
#define SS 4096
#define DD 1024
#define NN 128           // D / 8
#define KLV 8            // quantization levels
#define MM (BB*SS)       // 16384 rows
#define KC 2048          // x_cat width
#define KP 4096          // [hi | lo] padded width
#define NT 96            // virtual K tiles: 3 terms x 32 chunks of 64

typedef short bf16x8 __attribute__((ext_vector_type(8)));
typedef float f32x4 __attribute__((ext_vector_type(4)));

// Static device scratch.
__device__ float g_U[KLV * NN * 128];              // 512 KB  Cayley table
__device__ unsigned char g_levels[MM * NN];        // 2 MB    per-(token,block) level
__device__ unsigned short g_XHL[(size_t)MM * KP];  // 134 MB  [m][0..2047]=hi(x_cat), [2048..]=lo
__device__ unsigned short g_WT[(size_t)DD * KP];   // 8 MB    [n][0..2047]=wh, [2048..]=wl (W^T)

// f32 -> bf16 bits, round-to-nearest-even
__device__ __forceinline__ unsigned int bf16_bits(float f) {
    union { float f; unsigned int u; } v;
    v.f = f;
    unsigned int lsb = (v.u >> 16) & 1u;
    return (v.u + 0x7FFFu + lsb) >> 16;
}
__device__ __forceinline__ float bfbits2f(unsigned int b) {
    union { unsigned int u; float f; } v;
    v.u = b << 16;
    return v.f;
}

// async global->LDS 16B copy
__device__ __forceinline__ void gload16(const void* g, void* l) {
    __builtin_amdgcn_global_load_lds(
        (const __attribute__((address_space(1))) unsigned int*)g,
        (__attribute__((address_space(3))) unsigned int*)l, 16, 0, 0);
}

// ---------------------------------------------------------------------------
// prep_kernel: fused {convert_x | convert_wt | cayley} by blockIdx range.
// convert_x v2: one block per row m; 8 f32/thread; uint4 stores both planes.
// ---------------------------------------------------------------------------
#define WT_BLOCKS (64 * 32)
__global__ __launch_bounds__(256)
void prep_kernel(const float* __restrict__ xr, const float* __restrict__ xi,
                 const float* __restrict__ W,
                 const float* __restrict__ A_real,
                 const float* __restrict__ A_imag)
{
    __shared__ __align__(16) float sh[33 * 32];   // wt: tile[32][33]; cayley: M[16][34]
    int blk = blockIdx.x;
    int t = threadIdx.x;

    if (blk < MM) {
        // ---- convert_x: row m of x_cat (xr|xi) -> bf16 hi|lo planes ----
        int m = blk;
        int idx = t * 8;                 // 0..2040 within x_cat row
        int plane = idx >> 10;           // 0: xr, 1: xi
        int off = idx & 1023;
        const float* src = plane ? xi : xr;
        float4 v0 = *(const float4*)&src[(size_t)m * DD + off];
        float4 v1 = *(const float4*)&src[(size_t)m * DD + off + 4];
        float f[8] = {v0.x, v0.y, v0.z, v0.w, v1.x, v1.y, v1.z, v1.w};
        unsigned int hi[8], lo[8];
        #pragma unroll
        for (int q = 0; q < 8; ++q) {
            hi[q] = bf16_bits(f[q]);
            lo[q] = bf16_bits(f[q] - bfbits2f(hi[q]));
        }
        size_t base = (size_t)m * KP + plane * DD + off;
        *(uint4*)&g_XHL[base] = make_uint4(hi[0] | (hi[1] << 16), hi[2] | (hi[3] << 16),
                                           hi[4] | (hi[5] << 16), hi[6] | (hi[7] << 16));
        *(uint4*)&g_XHL[base + 2048] = make_uint4(lo[0] | (lo[1] << 16), lo[2] | (lo[3] << 16),
                                                  lo[4] | (lo[5] << 16), lo[6] | (lo[7] << 16));
        return;
    }
    blk -= MM;

    if (blk < WT_BLOCKS) {
        // ---- convert_wt: W[k][n] -> g_WT[n][k] bf16 hi|lo (32x32 transpose) ----
        float (*tile)[33] = (float(*)[33])sh;
        int bk = (blk >> 5) * 32;
        int bn = (blk & 31) * 32;

        int kk = t >> 3;
        int nn4 = (t & 7) * 4;
        float4 v = *(const float4*)&W[(size_t)(bk + kk) * DD + bn + nn4];
        tile[kk][nn4 + 0] = v.x; tile[kk][nn4 + 1] = v.y;
        tile[kk][nn4 + 2] = v.z; tile[kk][nn4 + 3] = v.w;
        __syncthreads();

        int n2 = t >> 3;
        int k4 = (t & 7) * 4;
        unsigned int hi[4], lo[4];
        #pragma unroll
        for (int q = 0; q < 4; ++q) {
            float f = tile[k4 + q][n2];
            hi[q] = bf16_bits(f);
            lo[q] = bf16_bits(f - bfbits2f(hi[q]));
        }
        size_t base = (size_t)(bn + n2) * KP + bk + k4;
        *(uint2*)&g_WT[base]        = make_uint2(hi[0] | (hi[1] << 16), hi[2] | (hi[3] << 16));
        *(uint2*)&g_WT[base + 2048] = make_uint2(lo[0] | (lo[1] << 16), lo[2] | (lo[3] << 16));
        return;
    }
    blk -= WT_BLOCKS;

    {
        // ---- cayley: Gauss-Jordan on 16x16 augmented system ----
        float (*M)[34] = (float(*)[34])sh;
        int L = blk >> 7;
        int n = blk & 127;
        float g = (float)L * (1.0f / 7.0f);

        int i = t >> 4;
        int j = t & 15;

        const float* Ar = A_real + n * 64;
        const float* Ai = A_imag + n * 64;
        int bi = i >> 3;
        int ii = i & 7, jj = j & 7;

        float ar = (Ar[ii * 8 + jj] - Ar[jj * 8 + ii]) * 0.5f * g;
        float ai = (Ai[ii * 8 + jj] + Ai[jj * 8 + ii]) * 0.5f * g;
        float eye = (ii == jj) ? 1.0f : 0.0f;

        int bj = j >> 3;
        float lhs, rhs;
        if (bi == bj) { lhs = eye + ar; rhs = eye - ar; }
        else if (bi == 0) { lhs = -ai; rhs = ai; }
        else { lhs = ai; rhs = -ai; }

        M[i][j] = lhs;
        M[i][16 + j] = rhs;
        __syncthreads();

        for (int k = 0; k < 16; ++k) {
            float f = M[i][k] / M[k][k];
            __syncthreads();
            if (i != k) {
                M[i][j]      -= f * M[k][j];
                M[i][16 + j] -= f * M[k][16 + j];
            }
            __syncthreads();
        }

        float x = M[i][16 + j] / M[i][i];
        if (j < 8) {
            g_U[(size_t)blk * 128 + bi * 64 + ii * 8 + j] = x;
        }
    }
}

// ---------------------------------------------------------------------------
// gate_mfma8: 256x256 tile, BK=64, 8 waves, counted-vmcnt pipeline,
// 2 barriers/tile, register-pipelined A-frag reads, and (round 14) the MFMA
// burst reordered kk-OUTERMOST: the two K-slice MFMAs hitting the same
// accumulator are separated by 8 independent MFMAs (dependency distance
// ~32 cyc > MFMA result latency) instead of issuing back-to-back.
// Virtual K = 96 tiles: chunk=kt/3, term=kt%3 (xh*wh, xl*wh, xh*wl).
// ---------------------------------------------------------------------------
__device__ __forceinline__ int colsA_of(int kt) {
    int k = (kt < NT) ? kt : 0;
    int ch = k / 3, tm = k - 3 * ch;
    return ch * 64 + (tm == 1 ? 2048 : 0);
}
__device__ __forceinline__ int colsB_of(int kt) {
    int k = (kt < NT) ? kt : 0;
    int ch = k / 3, tm = k - 3 * ch;
    return ch * 64 + (tm == 2 ? 2048 : 0);
}

__global__ __launch_bounds__(512, 1)
void gate_mfma8(const float* __restrict__ bias)
{
    __shared__ __align__(16) unsigned short lds[65536];   // 128 KB: 2 bufs x (A 16K + B 16K shorts)

    const int tid = threadIdx.x;
    const int bid = blockIdx.x;          // 0..255
    // bid%8 round-robins across XCDs [m09]; keep an m-strip's 4 n-tiles on
    // one XCD so the A-strip is fetched once into that XCD's L2.
    const int xcd = bid & 7;
    const int grp = bid >> 3;            // 0..31
    const int mt = xcd * 8 + (grp >> 2); // 0..63
    const int nt = grp & 3;              // 0..3
    const int bm = mt * 256, bn = nt * 256;

    const int lane = tid & 63;
    const int wv = tid >> 6;             // 8 waves: 2M x 4N
    const int wr = wv >> 2;              // 0..1
    const int wc = wv & 3;               // 0..3
    const int r16 = lane & 15, sgrp = lane >> 4;

    f32x4 acc[8][4];
    #pragma unroll
    for (int a = 0; a < 8; ++a)
        #pragma unroll
        for (int b = 0; b < 4; ++b) {
            f32x4 z = {0.0f, 0.0f, 0.0f, 0.0f};
            acc[a][b] = z;
        }

    // STAGE one half-tile (128 rows x 64 cols bf16 = 16KB): 2 gloads/thread.
    // Linear LDS dest; source col-unit pre-swizzled by ^(row&7)  [rule 21].
    #define STAGE(cbuf, isB, half, colbase, rowbase)                              \
    {                                                                             \
        const unsigned short* gsrc_ = (isB) ? g_WT : g_XHL;                       \
        _Pragma("unroll")                                                         \
        for (int h2 = 0; h2 < 2; ++h2) {                                          \
            int ck = h2 * 512 + tid;                                              \
            int row = ck >> 3, unit = ck & 7;                                     \
            int su = unit ^ (row & 7);                                            \
            gload16(&gsrc_[(size_t)((rowbase) + (half) * 128 + row) * KP          \
                           + (colbase) + su * 8],                                 \
                    &lds[(cbuf) * 32768 + (isB) * 16384 + (half) * 8192 + ck * 8]);\
        }                                                                         \
    }

    // Read phase-q A-frags into a named register buffer (static indexing).
    #define LOADA(dst, q)                                                         \
    {                                                                             \
        _Pragma("unroll")                                                         \
        for (int dm = 0; dm < 2; ++dm)                                            \
            _Pragma("unroll")                                                     \
            for (int kk = 0; kk < 2; ++kk) {                                      \
                int row = wr * 128 + ((q) * 2 + dm) * 16 + r16;                   \
                int u = kk * 4 + sgrp;                                            \
                (dst)[dm][kk] = *(const bf16x8*)&Abuf[row * 64 + (u ^ (row & 7)) * 8]; \
            }                                                                     \
    }

    // kk OUTER: 8 independent MFMAs between the two writes to any acc.
    #define MFMAQ(q, af)                                                          \
    {                                                                             \
        __builtin_amdgcn_s_setprio(1);                                            \
        _Pragma("unroll")                                                         \
        for (int kk = 0; kk < 2; ++kk)                                            \
            _Pragma("unroll")                                                     \
            for (int dm = 0; dm < 2; ++dm)                                        \
                _Pragma("unroll")                                                 \
                for (int ni = 0; ni < 4; ++ni)                                    \
                    acc[(q) * 2 + dm][ni] = __builtin_amdgcn_mfma_f32_16x16x32_bf16( \
                        (af)[dm][kk], bf[ni][kk], acc[(q) * 2 + dm][ni], 0, 0, 0);\
        __builtin_amdgcn_s_setprio(0);                                            \
    }

    // Prologue: tile0 fully + tile1 B; drain tile0 (8 loads), leave tile1-B (4).
    STAGE(0, 0, 0, colsA_of(0), bm); STAGE(0, 0, 1, colsA_of(0), bm);
    STAGE(0, 1, 0, colsB_of(0), bn); STAGE(0, 1, 1, colsB_of(0), bn);
    STAGE(1, 1, 0, colsB_of(1), bn); STAGE(1, 1, 1, colsB_of(1), bn);
    asm volatile("s_waitcnt vmcnt(4)" ::: "memory");
    __builtin_amdgcn_s_barrier();

    for (int kt = 0; kt < NT; ++kt) {
        const int cur = kt & 1;
        const int nxt = cur ^ 1;
        unsigned short* Abuf = &lds[cur * 32768];
        unsigned short* Bbuf = &lds[cur * 32768 + 16384];
        const int cA1 = colsA_of(kt + 1);
        const int cB2 = colsB_of(kt + 2);

        // Tile top: issue phase-0 A-frags, then all B-frags.
        bf16x8 af0[2][2], af1[2][2], bf[4][2];
        LOADA(af0, 0);
        #pragma unroll
        for (int ni = 0; ni < 4; ++ni)
            #pragma unroll
            for (int kk = 0; kk < 2; ++kk) {
                int row = wc * 64 + ni * 16 + r16;
                int u = kk * 4 + sgrp;
                bf[ni][kk] = *(const bf16x8*)&Bbuf[row * 64 + (u ^ (row & 7)) * 8];
            }

        // ---- phase 0: stage t+1.A0, prefetch A(q1), MFMA q0
        STAGE(nxt, 0, 0, cA1, bm);
        LOADA(af1, 1);
        MFMAQ(0, af0);
        // ---- phase 1: stage t+1.A1, prefetch A(q2), MFMA q1
        STAGE(nxt, 0, 1, cA1, bm);
        LOADA(af0, 2);
        MFMAQ(1, af1);
        // C1: cur-B consumed by all waves before q2's t+2-B stage overwrites.
        __builtin_amdgcn_s_barrier();
        // ---- phase 2: stage t+2.B0, prefetch A(q3), MFMA q2
        STAGE(cur, 1, 0, cB2, bn);
        LOADA(af1, 3);
        MFMAQ(2, af0);
        // ---- phase 3: stage t+2.B1, MFMA q3
        STAGE(cur, 1, 1, cB2, bn);
        MFMAQ(3, af1);
        // C3: drain own t+1-A stages (leave q2/q3's 4 B-loads in flight),
        // then collective barrier before any wave reads the nxt buffer.
        asm volatile("s_waitcnt vmcnt(4)" ::: "memory");
        __builtin_amdgcn_s_barrier();
    }
    asm volatile("s_waitcnt vmcnt(0)" ::: "memory");
    #undef STAGE
    #undef LOADA
    #undef MFMAQ

    // Epilogue: z = (c + bias)*1.7015 -> sigmoid -> mean over 8 cols -> level
    #pragma unroll
    for (int mi = 0; mi < 8; ++mi) {
        #pragma unroll
        for (int ni = 0; ni < 4; ++ni) {
            int n = bn + wc * 64 + ni * 16 + r16;
            float bb = bias[n];
            #pragma unroll
            for (int r = 0; r < 4; ++r) {
                float z = (acc[mi][ni][r] + bb) * 1.7015f;
                float s = 1.0f / (1.0f + expf(-z));
                s += __shfl_xor(s, 1);
                s += __shfl_xor(s, 2);
                s += __shfl_xor(s, 4);
                if ((lane & 7) == 0) {
                    float gcont = s * 0.125f;
                    int lvl = (int)rintf(gcont * 7.0f);
                    lvl = min(7, max(0, lvl));
                    int m = bm + wr * 128 + mi * 16 + sgrp * 4 + r;
                    g_levels[(size_t)m * NN + (n >> 3)] = (unsigned char)lvl;
                }
            }
        }
    }
}

// ---------------------------------------------------------------------------
// apply: gather U by level, rotate, blend, write bf16 pairs [imag, real].
// ---------------------------------------------------------------------------
__global__ __launch_bounds__(256)
void apply_kernel(const float* __restrict__ xr,
                  const float* __restrict__ xi,
                  unsigned short* __restrict__ out)
{
    int t = blockIdx.x * 256 + threadIdx.x;
    int bs = t >> 7;
    int n = t & 127;

    int L = g_levels[t];
    const float* Up = g_U + ((size_t)(L * NN + n)) * 128;
    const float* xrp = xr + (size_t)bs * DD + n * 8;
    const float* xip = xi + (size_t)bs * DD + n * 8;

    float4 r0 = *(const float4*)xrp;
    float4 r1 = *(const float4*)(xrp + 4);
    float4 i0 = *(const float4*)xip;
    float4 i1 = *(const float4*)(xip + 4);
    float xrv[8] = {r0.x, r0.y, r0.z, r0.w, r1.x, r1.y, r1.z, r1.w};
    float xiv[8] = {i0.x, i0.y, i0.z, i0.w, i1.x, i1.y, i1.z, i1.w};

    float gq = (float)L * (1.0f / 7.0f);
    float scale = gq / (gq + 1e-7f);

    unsigned int pk[8];
    #pragma unroll
    for (int oo = 0; oo < 8; ++oo) {
        float4 ur0 = *(const float4*)&Up[oo * 8];
        float4 ur1 = *(const float4*)&Up[oo * 8 + 4];
        float4 ui0 = *(const float4*)&Up[64 + oo * 8];
        float4 ui1 = *(const float4*)&Up[64 + oo * 8 + 4];
        float ur[8] = {ur0.x, ur0.y, ur0.z, ur0.w, ur1.x, ur1.y, ur1.z, ur1.w};
        float ui[8] = {ui0.x, ui0.y, ui0.z, ui0.w, ui1.x, ui1.y, ui1.z, ui1.w};
        float uxr = 0.0f, uxi = 0.0f;
        #pragma unroll
        for (int q = 0; q < 8; ++q) {
            uxr += ur[q] * xrv[q] - ui[q] * xiv[q];
            uxi += ur[q] * xiv[q] + ui[q] * xrv[q];
        }
        float outr = xrv[oo] + scale * (uxr - xrv[oo]);
        float outi = xiv[oo] + scale * (uxi - xiv[oo]);
        pk[oo] = bf16_bits(outi) | (bf16_bits(outr) << 16);   // [imag, real]
    }

    unsigned int* ob = (unsigned int*)(out + 2 * ((size_t)bs * DD + (size_t)n * 8));
    *(uint4*)&ob[0] = make_uint4(pk[0], pk[1], pk[2], pk[3]);
    *(uint4*)&ob[4] = make_uint4(pk[4], pk[5], pk[6], pk[7]);
}

// ---------------------------------------------------------------------------
extern "C" void kernel_launch(void* const* d_in, const int* in_sizes, int n_in,
                              void* d_out, int out_size, void* d_ws, size_t ws_size,
                              hipStream_t stream) {
    (void)in_sizes; (void)n_in; (void)out_size; (void)d_ws; (void)ws_size;
    const float* x_real = (const float*)d_in[0];
    const float* x_imag = (const float*)d_in[1];
    const float* A_real = (const float*)d_in[2];
    const float* A_imag = (const float*)d_in[3];
    const float* W_gate = (const float*)d_in[4];
    const float* b_gate = (const float*)d_in[5];
    unsigned short* out = (unsigned short*)d_out;

    hipLaunchKernelGGL(prep_kernel, dim3(MM + WT_BLOCKS + KLV * NN), dim3(256),
                       0, stream, x_real, x_imag, W_gate, A_real, A_imag);
    hipLaunchKernelGGL(gate_mfma8, dim3(256), dim3(512), 0, stream, b_gate);
    hipLaunchKernelGGL(apply_kernel, dim3((MM * NN) / 256), dim3(256), 0, stream,
                       x_real, x_imag, out);
}

// Round 15
// 340.294 us; speedup vs baseline: 2.8861x; 1.1370x over previous
//
#include <hip/hip_runtime.h>
#include <hip/hip_bf16.h>
#include <math.h>

// Problem constants
#define BB 4
#define SS 4096
#define DD 1024
#define NN 128           // D / 8
#define KLV 8            // quantization levels
#define MM (BB*SS)       // 16384 rows
#define NST 64           // K substeps of 32 over x_cat (2048)

typedef short bf16x8 __attribute__((ext_vector_type(8)));
typedef float f32x4 __attribute__((ext_vector_type(4)));

// Static device scratch.
__device__ float g_U[KLV * NN * 128];              // 512 KB Cayley table
__device__ unsigned char g_levels[MM * NN];        // 2 MB   per-(token,block) level
// W pre-subtiled into the gate's exact LDS image:
// elem index = (((st*2 + plane)*4 + kgrp)*1024 + n)*8 + kin   (8 MB)
__device__ unsigned short g_WTs[(size_t)NST * 2 * 4 * 1024 * 8];

// f32 -> bf16 bits, round-to-nearest-even
__device__ __forceinline__ unsigned int bf16_bits(float f) {
    union { float f; unsigned int u; } v;
    v.f = f;
    unsigned int lsb = (v.u >> 16) & 1u;
    return (v.u + 0x7FFFu + lsb) >> 16;
}
__device__ __forceinline__ float bfbits2f(unsigned int b) {
    union { unsigned int u; float f; } v;
    v.u = b << 16;
    return v.f;
}

// async global->LDS 16B copy (dest: wave-uniform base + lane*16)
__device__ __forceinline__ void gload16(const void* g, void* l) {
    __builtin_amdgcn_global_load_lds(
        (const __attribute__((address_space(1))) unsigned int*)g,
        (__attribute__((address_space(3))) unsigned int*)l, 16, 0, 0);
}

// ---------------------------------------------------------------------------
// prep_kernel: {convert_wt | cayley} by blockIdx range (convert_x is gone —
// the x hi/lo split is fused into gate_fused).
// ---------------------------------------------------------------------------
#define WT_BLOCKS (64 * 32)
__global__ __launch_bounds__(256)
void prep_kernel(const float* __restrict__ W,
                 const float* __restrict__ A_real,
                 const float* __restrict__ A_imag)
{
    __shared__ __align__(16) float sh[33 * 32];
    int blk = blockIdx.x;
    int t = threadIdx.x;

    if (blk < WT_BLOCKS) {
        // ---- convert_wt: W[k][n] -> g_WTs subtiled hi|lo (32x32 transpose) ----
        float (*tile)[33] = (float(*)[33])sh;
        int bk = (blk >> 5) * 32;
        int bn = (blk & 31) * 32;

        int kk = t >> 3;
        int nn4 = (t & 7) * 4;
        float4 v = *(const float4*)&W[(size_t)(bk + kk) * DD + bn + nn4];
        tile[kk][nn4 + 0] = v.x; tile[kk][nn4 + 1] = v.y;
        tile[kk][nn4 + 2] = v.z; tile[kk][nn4 + 3] = v.w;
        __syncthreads();

        int n2 = t >> 3;                   // 0..31 (output n within tile)
        int k4i = (t & 7) * 4;             // 0..28, 4 consecutive k
        unsigned int hi[4], lo[4];
        #pragma unroll
        for (int q = 0; q < 4; ++q) {
            float f = tile[k4i + q][n2];
            hi[q] = bf16_bits(f);
            lo[q] = bf16_bits(f - bfbits2f(hi[q]));
        }
        int st = bk >> 5;
        int kgrp = (k4i >> 3) & 3;
        int kin = k4i & 7;                 // 0 or 4
        int n = bn + n2;
        size_t bh = ((size_t)((st * 2 + 0) * 4 + kgrp) * 1024 + n) * 8 + kin;
        size_t bl = ((size_t)((st * 2 + 1) * 4 + kgrp) * 1024 + n) * 8 + kin;
        *(uint2*)&g_WTs[bh] = make_uint2(hi[0] | (hi[1] << 16), hi[2] | (hi[3] << 16));
        *(uint2*)&g_WTs[bl] = make_uint2(lo[0] | (lo[1] << 16), lo[2] | (lo[3] << 16));
        return;
    }
    blk -= WT_BLOCKS;

    {
        // ---- cayley: Gauss-Jordan on 16x16 augmented system ----
        float (*M)[34] = (float(*)[34])sh;
        int L = blk >> 7;
        int n = blk & 127;
        float g = (float)L * (1.0f / 7.0f);

        int i = t >> 4;
        int j = t & 15;

        const float* Ar = A_real + n * 64;
        const float* Ai = A_imag + n * 64;
        int bi = i >> 3;
        int ii = i & 7, jj = j & 7;

        float ar = (Ar[ii * 8 + jj] - Ar[jj * 8 + ii]) * 0.5f * g;
        float ai = (Ai[ii * 8 + jj] + Ai[jj * 8 + ii]) * 0.5f * g;
        float eye = (ii == jj) ? 1.0f : 0.0f;

        int bj = j >> 3;
        float lhs, rhs;
        if (bi == bj) { lhs = eye + ar; rhs = eye - ar; }
        else if (bi == 0) { lhs = -ai; rhs = ai; }
        else { lhs = ai; rhs = -ai; }

        M[i][j] = lhs;
        M[i][16 + j] = rhs;
        __syncthreads();

        for (int k = 0; k < 16; ++k) {
            float f = M[i][k] / M[k][k];
            __syncthreads();
            if (i != k) {
                M[i][j]      -= f * M[k][j];
                M[i][16 + j] -= f * M[k][16 + j];
            }
            __syncthreads();
        }

        float x = M[i][16 + j] / M[i][i];
        if (j < 8) {
            g_U[(size_t)blk * 128 + bi * 64 + ii * 8 + j] = x;
        }
    }
}

// ---------------------------------------------------------------------------
// gate_fused: 256x256 tile, 8 waves, K=32 substeps. Stages raw f32 x,
// converts to bf16 hi|lo in-register, writes subtiled LDS tiles ONCE per
// substep shared by all 3 terms (xh*wh, xl*wh, xh*wl). B staged linear via
// gload_lds from pre-subtiled g_WTs. 1 barrier + 1 vmcnt(0) per substep.
// LDS map per buf (shorts): A_hi[4][256][8] @0, A_lo @8192, wh @16384, wl @24576.
// ---------------------------------------------------------------------------
__global__ __launch_bounds__(512, 1)
void gate_fused(const float* __restrict__ xr, const float* __restrict__ xi,
                const float* __restrict__ bias)
{
    __shared__ __align__(16) unsigned short lds[65536];   // 128 KB = 2 bufs x 64KB

    const int tid = threadIdx.x;
    const int bid = blockIdx.x;          // 0..255
    const int xcd = bid & 7;             // dispatch round-robins XCDs [m09]
    const int grp = bid >> 3;            // 0..31
    const int mt = xcd * 8 + (grp >> 2); // 0..63 : 4 n-tiles of an m-strip
    const int nt = grp & 3;              //         co-resident on one XCD
    const int bm = mt * 256, bn = nt * 256;

    const int lane = tid & 63;
    const int wv = tid >> 6;             // 8 waves: 2M x 4N
    const int wr = wv >> 2;
    const int wc = wv & 3;
    const int r16 = lane & 15, sgrp = lane >> 4;

    const int arow = tid >> 1;           // staging row 0..255
    const int kb = (tid & 1) * 2;        // staging kgrp base (0 or 2)

    f32x4 acc[8][4];
    #pragma unroll
    for (int a = 0; a < 8; ++a)
        #pragma unroll
        for (int b = 0; b < 4; ++b) {
            f32x4 z = {0.0f, 0.0f, 0.0f, 0.0f};
            acc[a][b] = z;
        }

    // Load 16 f32 of substep s (clamped) into 4 float4 regs.
    #define LOADX(dst, s)                                                         \
    {                                                                             \
        int s_ = (s) > 63 ? 63 : (s);                                             \
        int k0_ = s_ * 32;                                                        \
        const float* src_ = (k0_ < 1024) ? xr : xi;                               \
        const float* p_ = src_ + (size_t)(bm + arow) * DD + (k0_ & 1023)          \
                          + (tid & 1) * 16;                                       \
        (dst)[0] = *(const float4*)(p_);                                          \
        (dst)[1] = *(const float4*)(p_ + 4);                                      \
        (dst)[2] = *(const float4*)(p_ + 8);                                      \
        (dst)[3] = *(const float4*)(p_ + 12);                                     \
    }

    // Convert 16 f32 -> hi/lo bf16, write 4x b128 into buffer base bb (shorts).
    #define WRITEA(fv, bb)                                                        \
    {                                                                             \
        float ff_[16] = {(fv)[0].x, (fv)[0].y, (fv)[0].z, (fv)[0].w,              \
                         (fv)[1].x, (fv)[1].y, (fv)[1].z, (fv)[1].w,              \
                         (fv)[2].x, (fv)[2].y, (fv)[2].z, (fv)[2].w,              \
                         (fv)[3].x, (fv)[3].y, (fv)[3].z, (fv)[3].w};             \
        unsigned int h_[16], l_[16];                                              \
        _Pragma("unroll")                                                         \
        for (int q = 0; q < 16; ++q) {                                            \
            h_[q] = bf16_bits(ff_[q]);                                            \
            l_[q] = bf16_bits(ff_[q] - bfbits2f(h_[q]));                          \
        }                                                                         \
        _Pragma("unroll")                                                         \
        for (int b2 = 0; b2 < 2; ++b2) {                                          \
            int o_ = ((kb + b2) * 256 + arow) * 8;                                \
            *(uint4*)&lds[(bb) + o_] = make_uint4(                                \
                h_[b2*8+0] | (h_[b2*8+1] << 16), h_[b2*8+2] | (h_[b2*8+3] << 16), \
                h_[b2*8+4] | (h_[b2*8+5] << 16), h_[b2*8+6] | (h_[b2*8+7] << 16));\
            *(uint4*)&lds[(bb) + 8192 + o_] = make_uint4(                         \
                l_[b2*8+0] | (l_[b2*8+1] << 16), l_[b2*8+2] | (l_[b2*8+3] << 16), \
                l_[b2*8+4] | (l_[b2*8+5] << 16), l_[b2*8+6] | (l_[b2*8+7] << 16));\
        }                                                                         \
    }

    // Stage B (wh+wl 32KB) of substep s into buffer base bb via gload_lds.
    #define STAGEB(s, bb)                                                         \
    {                                                                             \
        int s_ = (s) > 63 ? 63 : (s);                                             \
        _Pragma("unroll")                                                         \
        for (int l2 = 0; l2 < 2; ++l2) {                                          \
            int o16_ = (wv * 2 + l2) * 64 + lane;                                 \
            int kg_ = o16_ >> 8, nl_ = o16_ & 255;                                \
            size_t sh_ = ((size_t)((s_ * 2 + 0) * 4 + kg_) * 1024 + bn + nl_) * 8;\
            size_t sl_ = ((size_t)((s_ * 2 + 1) * 4 + kg_) * 1024 + bn + nl_) * 8;\
            gload16(&g_WTs[sh_], &lds[(bb) + 16384 + (wv * 2 + l2) * 512]);       \
            gload16(&g_WTs[sl_], &lds[(bb) + 24576 + (wv * 2 + l2) * 512]);       \
        }                                                                         \
    }

    #define RA(bb, plane, mi) (*(const bf16x8*)&lds[(bb) + (plane) * 8192 + \
        (sgrp * 256 + wr * 128 + (mi) * 16 + r16) * 8])
    #define RB(bb, plane, ni) (*(const bf16x8*)&lds[(bb) + 16384 + (plane) * 8192 + \
        (sgrp * 256 + wc * 64 + (ni) * 16 + r16) * 8])

    // ---- Prologue: stage substep 0 into buf0; preload f32(1). ----
    float4 fst[4], ftmp[4];
    LOADX(fst, 0);
    asm volatile("s_waitcnt vmcnt(0)" ::: "memory");
    WRITEA(fst, 0);
    STAGEB(0, 0);
    LOADX(fst, 1);
    asm volatile("s_waitcnt vmcnt(0) lgkmcnt(0)" ::: "memory");
    __builtin_amdgcn_s_barrier();

    for (int st = 0; st < NST; ++st) {
        const int bcur = (st & 1) * 32768;
        const int bnxt = bcur ^ 32768;

        // Stage st+1 into nxt; issue f32(st+2).
        WRITEA(fst, bnxt);
        STAGEB(st + 1, bnxt);
        LOADX(ftmp, st + 2);

        // Compute st from cur: 3 terms x 32 MFMA.
        bf16x8 whf[4], wlf[4], a8[8];
        #pragma unroll
        for (int ni = 0; ni < 4; ++ni) whf[ni] = RB(bcur, 0, ni);
        #pragma unroll
        for (int mi = 0; mi < 8; ++mi) a8[mi] = RA(bcur, 0, mi);
        __builtin_amdgcn_s_setprio(1);
        #pragma unroll
        for (int mi = 0; mi < 8; ++mi)
            #pragma unroll
            for (int ni = 0; ni < 4; ++ni)
                acc[mi][ni] = __builtin_amdgcn_mfma_f32_16x16x32_bf16(
                    a8[mi], whf[ni], acc[mi][ni], 0, 0, 0);
        __builtin_amdgcn_s_setprio(0);
        #pragma unroll
        for (int mi = 0; mi < 8; ++mi) a8[mi] = RA(bcur, 1, mi);   // lo
        __builtin_amdgcn_s_setprio(1);
        #pragma unroll
        for (int mi = 0; mi < 8; ++mi)
            #pragma unroll
            for (int ni = 0; ni < 4; ++ni)
                acc[mi][ni] = __builtin_amdgcn_mfma_f32_16x16x32_bf16(
                    a8[mi], whf[ni], acc[mi][ni], 0, 0, 0);
        __builtin_amdgcn_s_setprio(0);
        #pragma unroll
        for (int ni = 0; ni < 4; ++ni) wlf[ni] = RB(bcur, 1, ni);
        #pragma unroll
        for (int mi = 0; mi < 8; ++mi) a8[mi] = RA(bcur, 0, mi);   // hi again
        __builtin_amdgcn_s_setprio(1);
        #pragma unroll
        for (int mi = 0; mi < 8; ++mi)
            #pragma unroll
            for (int ni = 0; ni < 4; ++ni)
                acc[mi][ni] = __builtin_amdgcn_mfma_f32_16x16x32_bf16(
                    a8[mi], wlf[ni], acc[mi][ni], 0, 0, 0);
        __builtin_amdgcn_s_setprio(0);

        // End of substep: B(st+1)+f32(st+2) drained; all waves synced.
        asm volatile("s_waitcnt vmcnt(0)" ::: "memory");
        __builtin_amdgcn_s_barrier();
        #pragma unroll
        for (int q = 0; q < 4; ++q) fst[q] = ftmp[q];
    }
    #undef LOADX
    #undef WRITEA
    #undef STAGEB
    #undef RA
    #undef RB

    // Epilogue: z = (c + bias)*1.7015 -> sigmoid -> mean over 8 cols -> level
    #pragma unroll
    for (int mi = 0; mi < 8; ++mi) {
        #pragma unroll
        for (int ni = 0; ni < 4; ++ni) {
            int n = bn + wc * 64 + ni * 16 + r16;
            float bb = bias[n];
            #pragma unroll
            for (int r = 0; r < 4; ++r) {
                float z = (acc[mi][ni][r] + bb) * 1.7015f;
                float s = 1.0f / (1.0f + expf(-z));
                s += __shfl_xor(s, 1);
                s += __shfl_xor(s, 2);
                s += __shfl_xor(s, 4);
                if ((lane & 7) == 0) {
                    float gcont = s * 0.125f;
                    int lvl = (int)rintf(gcont * 7.0f);
                    lvl = min(7, max(0, lvl));
                    int m = bm + wr * 128 + mi * 16 + sgrp * 4 + r;
                    g_levels[(size_t)m * NN + (n >> 3)] = (unsigned char)lvl;
                }
            }
        }
    }
}

// ---------------------------------------------------------------------------
// apply: gather U by level, rotate, blend, write bf16 pairs [imag, real].
// ---------------------------------------------------------------------------
__global__ __launch_bounds__(256)
void apply_kernel(const float* __restrict__ xr,
                  const float* __restrict__ xi,
                  unsigned short* __restrict__ out)
{
    int t = blockIdx.x * 256 + threadIdx.x;
    int bs = t >> 7;
    int n = t & 127;

    int L = g_levels[t];
    const float* Up = g_U + ((size_t)(L * NN + n)) * 128;
    const float* xrp = xr + (size_t)bs * DD + n * 8;
    const float* xip = xi + (size_t)bs * DD + n * 8;

    float4 r0 = *(const float4*)xrp;
    float4 r1 = *(const float4*)(xrp + 4);
    float4 i0 = *(const float4*)xip;
    float4 i1 = *(const float4*)(xip + 4);
    float xrv[8] = {r0.x, r0.y, r0.z, r0.w, r1.x, r1.y, r1.z, r1.w};
    float xiv[8] = {i0.x, i0.y, i0.z, i0.w, i1.x, i1.y, i1.z, i1.w};

    float gq = (float)L * (1.0f / 7.0f);
    float scale = gq / (gq + 1e-7f);

    unsigned int pk[8];
    #pragma unroll
    for (int oo = 0; oo < 8; ++oo) {
        float4 ur0 = *(const float4*)&Up[oo * 8];
        float4 ur1 = *(const float4*)&Up[oo * 8 + 4];
        float4 ui0 = *(const float4*)&Up[64 + oo * 8];
        float4 ui1 = *(const float4*)&Up[64 + oo * 8 + 4];
        float ur[8] = {ur0.x, ur0.y, ur0.z, ur0.w, ur1.x, ur1.y, ur1.z, ur1.w};
        float ui[8] = {ui0.x, ui0.y, ui0.z, ui0.w, ui1.x, ui1.y, ui1.z, ui1.w};
        float uxr = 0.0f, uxi = 0.0f;
        #pragma unroll
        for (int q = 0; q < 8; ++q) {
            uxr += ur[q] * xrv[q] - ui[q] * xiv[q];
            uxi += ur[q] * xiv[q] + ui[q] * xrv[q];
        }
        float outr = xrv[oo] + scale * (uxr - xrv[oo]);
        float outi = xiv[oo] + scale * (uxi - xiv[oo]);
        pk[oo] = bf16_bits(outi) | (bf16_bits(outr) << 16);   // [imag, real]
    }

    unsigned int* ob = (unsigned int*)(out + 2 * ((size_t)bs * DD + (size_t)n * 8));
    *(uint4*)&ob[0] = make_uint4(pk[0], pk[1], pk[2], pk[3]);
    *(uint4*)&ob[4] = make_uint4(pk[4], pk[5], pk[6], pk[7]);
}

// ---------------------------------------------------------------------------
extern "C" void kernel_launch(void* const* d_in, const int* in_sizes, int n_in,
                              void* d_out, int out_size, void* d_ws, size_t ws_size,
                              hipStream_t stream) {
    (void)in_sizes; (void)n_in; (void)out_size; (void)d_ws; (void)ws_size;
    const float* x_real = (const float*)d_in[0];
    const float* x_imag = (const float*)d_in[1];
    const float* A_real = (const float*)d_in[2];
    const float* A_imag = (const float*)d_in[3];
    const float* W_gate = (const float*)d_in[4];
    const float* b_gate = (const float*)d_in[5];
    unsigned short* out = (unsigned short*)d_out;

    hipLaunchKernelGGL(prep_kernel, dim3(WT_BLOCKS + KLV * NN), dim3(256),
                       0, stream, W_gate, A_real, A_imag);
    hipLaunchKernelGGL(gate_fused, dim3(256), dim3(512), 0, stream,
                       x_real, x_imag, b_gate);
    hipLaunchKernelGGL(apply_kernel, dim3((MM * NN) / 256), dim3(256), 0, stream,
                       x_real, x_imag, out);
}